// Round 4
// baseline (2892.117 us; speedup 1.0000x reference)
//
#include <hip/hip_runtime.h>
#include <hip/hip_bf16.h>

#define DEV_INLINE __device__ __forceinline__

typedef short s16x8 __attribute__((ext_vector_type(8)));
typedef float f32x4 __attribute__((ext_vector_type(4)));
typedef unsigned short u16x4 __attribute__((ext_vector_type(4)));

DEV_INLINE float gelu_exact(float x) {
    return 0.5f * x * (1.0f + erff(x * 0.70710678118654752440f));
}
DEV_INLINE double gelu64(double x) {
    return 0.5 * x * (1.0 + erf(x * 0.70710678118654752440));
}
DEV_INLINE unsigned short f2bf_rne(float f) {
    unsigned u = __float_as_uint(f);
    unsigned r = u + 0x7FFFu + ((u >> 16) & 1u);
    return (unsigned short)(r >> 16);
}
DEV_INLINE float bf2f(unsigned short h) { return __uint_as_float(((unsigned)h) << 16); }

// ---------------- conv1 (f64): ts (16,100,2048) f32 -> relu(causal conv d=1) -> h1 (16,64,2048) f64
__global__ __launch_bounds__(256) void conv1_kernel64(
    const float* __restrict__ x, const float* __restrict__ w,
    const float* __restrict__ bias, double* __restrict__ y)
{
    const int b = blockIdx.y;
    const int t0 = blockIdx.x * 32;
    __shared__ double xs[100][34];
    for (int e = threadIdx.x; e < 100 * 34; e += 256) {
        int i = e / 34, u = e - i * 34;
        int t = t0 - 2 + u;
        xs[i][u] = (t >= 0) ? (double)x[(b * 100 + i) * 2048 + t] : 0.0;
    }
    __syncthreads();
    const int o = threadIdx.x & 63;
    const int ts = (threadIdx.x >> 6) * 8;
    double acc[8];
    double bv = (double)bias[o];
#pragma unroll
    for (int j = 0; j < 8; ++j) acc[j] = bv;
    const float* wo = w + o * 300;
    for (int i = 0; i < 100; ++i) {
        double w0 = (double)wo[i * 3 + 0], w1 = (double)wo[i * 3 + 1], w2 = (double)wo[i * 3 + 2];
#pragma unroll
        for (int j = 0; j < 8; ++j) {
            acc[j] = fma(w0, xs[i][ts + j],
                     fma(w1, xs[i][ts + j + 1],
                     fma(w2, xs[i][ts + j + 2], acc[j])));
        }
    }
#pragma unroll
    for (int j = 0; j < 8; ++j)
        y[(b * 64 + o) * 2048 + t0 + ts + j] = fmax(acc[j], 0.0);
}

// ---------------- conv2 (f64): h1 -> relu(causal conv d=2) -> xt64 (16,2048,128) transposed
__global__ __launch_bounds__(256) void conv2_kernel64(
    const double* __restrict__ x, const float* __restrict__ w,
    const float* __restrict__ bias, double* __restrict__ xt)
{
    const int b = blockIdx.y;
    const int t0 = blockIdx.x * 32;
    __shared__ double xs[64][36];
    for (int e = threadIdx.x; e < 64 * 36; e += 256) {
        int i = e / 36, u = e - i * 36;
        int t = t0 - 4 + u;
        xs[i][u] = (t >= 0) ? x[(b * 64 + i) * 2048 + t] : 0.0;
    }
    __syncthreads();
    const int o = threadIdx.x & 127;
    const int ts = (threadIdx.x >> 7) * 16;
    double acc[16];
    double bv = (double)bias[o];
#pragma unroll
    for (int j = 0; j < 16; ++j) acc[j] = bv;
    const float* wo = w + o * 192;
    for (int i = 0; i < 64; ++i) {
        double w0 = (double)wo[i * 3 + 0], w1 = (double)wo[i * 3 + 1], w2 = (double)wo[i * 3 + 2];
#pragma unroll
        for (int j = 0; j < 16; ++j) {
            acc[j] = fma(w0, xs[i][ts + j],
                     fma(w1, xs[i][ts + j + 2],
                     fma(w2, xs[i][ts + j + 4], acc[j])));
        }
    }
#pragma unroll
    for (int j = 0; j < 16; ++j)
        xt[(size_t)(b * 2048 + t0 + ts + j) * 128 + o] = fmax(acc[j], 0.0);
}

// ---------------- norm32: from xt64, emit xn32 (f64-normalized, f32-rounded)
__global__ __launch_bounds__(256) void norm32_kernel(
    const double* __restrict__ xt64, float* __restrict__ xn)
{
    const int row = blockIdx.x * 4 + (threadIdx.x >> 6);
    const int lane = threadIdx.x & 63;
    double v0 = xt64[(size_t)row * 128 + lane * 2];
    double v1 = xt64[(size_t)row * 128 + lane * 2 + 1];
    double s = v0 * v0 + v1 * v1;
#pragma unroll
    for (int off = 32; off > 0; off >>= 1) s += __shfl_xor(s, off);
    double inv = 1.0 / fmax(sqrt(s), 1e-12);
    xn[(size_t)row * 128 + lane * 2]     = (float)(v0 * inv);
    xn[(size_t)row * 128 + lane * 2 + 1] = (float)(v1 * inv);
}

// ---------------- knn stage 1 (bf16x3-split MFMA): per (b,n) top-16 CANDIDATES by dot
// block 256 thr / 4 waves; 64 rows per block; m-tiles of 128; gram via 6-term MFMA.
__global__ __launch_bounds__(256) void knn_mfma_kernel(
    const float* __restrict__ xn, int* __restrict__ cand_out)
{
    __shared__ __align__(16) unsigned char smem[147456];  // 144 KB
    unsigned char* RaH = smem;                 // 64x128 bf16, swizzled
    unsigned char* RaM = smem + 16384;
    unsigned char* RaL = smem + 32768;
    unsigned char* MaH = smem + 49152;         // 128x128 bf16, swizzled
    unsigned char* MaM = smem + 81920;
    unsigned char* MaL = smem + 114688;

    const int b = blockIdx.y;
    const int n0 = blockIdx.x * 64;
    const float* Xb = xn + (size_t)b * 2048 * 128;

    const int tid = threadIdx.x;
    const int wave = tid >> 6, lane = tid & 63;

    // stage Ra (64 rows) as hi/mid/lo bf16 planes, XOR-swizzled
    for (int e = tid; e < 64 * 32; e += 256) {
        int r = e >> 5, q = e & 31;
        float4 v = *(const float4*)(Xb + (size_t)(n0 + r) * 128 + q * 4);
        float f[4] = {v.x, v.y, v.z, v.w};
        u16x4 hv, mv, lv;
#pragma unroll
        for (int j = 0; j < 4; ++j) {
            unsigned short h = f2bf_rne(f[j]);
            float r1 = f[j] - bf2f(h);
            unsigned short m = f2bf_rne(r1);
            unsigned short l = f2bf_rne(r1 - bf2f(m));
            hv[j] = h; mv[j] = m; lv[j] = l;
        }
        int swz = (r * 256 + q * 8) ^ ((r & 7) << 4);
        *(u16x4*)(RaH + swz) = hv;
        *(u16x4*)(RaM + swz) = mv;
        *(u16x4*)(RaL + swz) = lv;
    }

    float tv[4][9];
    int   ti[4][9];
#pragma unroll
    for (int q = 0; q < 4; ++q)
#pragma unroll
        for (int t = 0; t < 9; ++t) { tv[q][t] = -3.0e38f; ti[q][t] = 0x3FFFFFFF; }

    const int arow = wave * 16 + (lane & 15);
    const int g16 = (lane >> 4) * 16;

    for (int m0t = 0; m0t < 2048; m0t += 128) {
        __syncthreads();
        for (int e = tid; e < 128 * 32; e += 256) {
            int r = e >> 5, q = e & 31;
            float4 v = *(const float4*)(Xb + (size_t)(m0t + r) * 128 + q * 4);
            float f[4] = {v.x, v.y, v.z, v.w};
            u16x4 hv, mv, lv;
#pragma unroll
            for (int j = 0; j < 4; ++j) {
                unsigned short h = f2bf_rne(f[j]);
                float r1 = f[j] - bf2f(h);
                unsigned short m = f2bf_rne(r1);
                unsigned short l = f2bf_rne(r1 - bf2f(m));
                hv[j] = h; mv[j] = m; lv[j] = l;
            }
            int swz = (r * 256 + q * 8) ^ ((r & 7) << 4);
            *(u16x4*)(MaH + swz) = hv;
            *(u16x4*)(MaM + swz) = mv;
            *(u16x4*)(MaL + swz) = lv;
        }
        __syncthreads();

        f32x4 acc[8];
#pragma unroll
        for (int ct = 0; ct < 8; ++ct) { acc[ct][0] = 0.f; acc[ct][1] = 0.f; acc[ct][2] = 0.f; acc[ct][3] = 0.f; }

#pragma unroll
        for (int s = 0; s < 4; ++s) {
            int aoff = (arow * 256 + s * 64 + g16) ^ ((arow & 7) << 4);
            s16x8 aH = *(const s16x8*)(RaH + aoff);
            s16x8 aM = *(const s16x8*)(RaM + aoff);
            s16x8 aL = *(const s16x8*)(RaL + aoff);
#pragma unroll
            for (int ct = 0; ct < 8; ++ct) {
                int mrow = ct * 16 + (lane & 15);
                int boff = (mrow * 256 + s * 64 + g16) ^ ((mrow & 7) << 4);
                s16x8 bH = *(const s16x8*)(MaH + boff);
                s16x8 bM = *(const s16x8*)(MaM + boff);
                s16x8 bL = *(const s16x8*)(MaL + boff);
                acc[ct] = __builtin_amdgcn_mfma_f32_16x16x32_bf16(aH, bH, acc[ct], 0, 0, 0);
                acc[ct] = __builtin_amdgcn_mfma_f32_16x16x32_bf16(aH, bM, acc[ct], 0, 0, 0);
                acc[ct] = __builtin_amdgcn_mfma_f32_16x16x32_bf16(aM, bH, acc[ct], 0, 0, 0);
                acc[ct] = __builtin_amdgcn_mfma_f32_16x16x32_bf16(aM, bM, acc[ct], 0, 0, 0);
                acc[ct] = __builtin_amdgcn_mfma_f32_16x16x32_bf16(aH, bL, acc[ct], 0, 0, 0);
                acc[ct] = __builtin_amdgcn_mfma_f32_16x16x32_bf16(aL, bH, acc[ct], 0, 0, 0);
            }
        }

        // selection: lane holds rows (wave*16 + (lane>>4)*4 + q), col = m0t + ct*16 + (lane&15)
#pragma unroll
        for (int ct = 0; ct < 8; ++ct) {
            int mg = m0t + ct * 16 + (lane & 15);
#pragma unroll
            for (int q = 0; q < 4; ++q) {
                float candv = acc[ct][q];
                if (candv > tv[q][8]) {    // in-order arrival => strict '>' keeps lower index on ties
                    tv[q][8] = candv; ti[q][8] = mg;
#pragma unroll
                    for (int t = 8; t > 0; --t) {
                        if (tv[q][t] > tv[q][t - 1]) {
                            float tmpv = tv[q][t]; tv[q][t] = tv[q][t - 1]; tv[q][t - 1] = tmpv;
                            int tmpi = ti[q][t]; ti[q][t] = ti[q][t - 1]; ti[q][t - 1] = tmpi;
                        }
                    }
                }
            }
        }
    }
    __syncthreads();

    // merge 16 per-lane lists per row -> top-16 candidates (reuse LDS)
    float* mV = (float*)smem;
    int*   mI = (int*)(smem + 37120);
    {
        int rbase = wave * 16 + (lane >> 4) * 4;
        int slot = lane & 15;
#pragma unroll
        for (int q = 0; q < 4; ++q)
#pragma unroll
            for (int t = 0; t < 9; ++t) {
                mV[(rbase + q) * 145 + slot * 9 + t] = tv[q][t];
                mI[(rbase + q) * 145 + slot * 9 + t] = ti[q][t];
            }
    }
    __syncthreads();
    if (tid < 64) {
        float* V = mV + tid * 145;
        int*   I = mI + tid * 145;
        size_t outbase = ((size_t)(b * 2048) + n0 + tid) * 16;
        for (int pass = 0; pass < 16; ++pass) {
            float best = -3.4e38f; int bi = 1 << 30; int bp = 0;
            for (int j = 0; j < 144; ++j) {
                float v = V[j];
                int id = I[j];
                if (v > best || (v == best && id < bi)) { best = v; bi = id; bp = j; }
            }
            V[bp] = -3.4e38f;
            cand_out[outbase + pass] = bi;
        }
    }
}

// ---------------- knn stage 2 (f64): exact rescore of 16 candidates, pick top-9 (stable ties)
__global__ __launch_bounds__(256) void rescore_kernel(
    const double* __restrict__ xt64, const int* __restrict__ cand, int* __restrict__ idx_out)
{
    const int wid = threadIdx.x >> 6, lane = threadIdx.x & 63;
    const int n = blockIdx.x * 4 + wid;
    const int b = n >> 11;
    const double* Xb = xt64 + (size_t)b * 2048 * 128;
    const double* xr = xt64 + (size_t)n * 128;
    double a0 = xr[lane * 2], a1 = xr[lane * 2 + 1];
    double snn = a0 * a0 + a1 * a1;
#pragma unroll
    for (int off = 32; off > 0; off >>= 1) snn += __shfl_xor(snn, off);
    double invn = 1.0 / fmax(sqrt(snn), 1e-12);
    double sc[16]; int cd[16];
#pragma unroll
    for (int k = 0; k < 16; ++k) {
        int m = cand[(size_t)n * 16 + k];
        const double* xm = Xb + (size_t)m * 128;
        double m0v = xm[lane * 2], m1v = xm[lane * 2 + 1];
        double dnm = a0 * m0v + a1 * m1v;
        double dmm = m0v * m0v + m1v * m1v;
#pragma unroll
        for (int off = 32; off > 0; off >>= 1) {
            dnm += __shfl_xor(dnm, off);
            dmm += __shfl_xor(dmm, off);
        }
        double invm = 1.0 / fmax(sqrt(dmm), 1e-12);
        sc[k] = 2.0 * dnm * invn * invm - dmm * invm * invm;
        cd[k] = m;
    }
    if (lane == 0) {
        unsigned usedmask = 0;
        size_t ob = (size_t)n * 9;
        for (int p = 0; p < 9; ++p) {
            double best = -1.0e300; int bi = 1 << 30; int bp = 0;
#pragma unroll
            for (int j = 0; j < 16; ++j) {
                if (usedmask & (1u << j)) continue;
                if (sc[j] > best || (sc[j] == best && cd[j] < bi)) { best = sc[j]; bi = cd[j]; bp = j; }
            }
            usedmask |= 1u << bp;
            idx_out[ob + p] = bi;
        }
    }
}

// ---------------- f64 GEMM (K=128). mode 0: G=Xt@[W1;W2]^T (ld 256); 1: gelu affine; 2: affine (+f32 copy)
__global__ __launch_bounds__(256) void gemm64_kernel(
    const double* __restrict__ A, const float* __restrict__ W,
    const float* __restrict__ bias, const float* __restrict__ gamma,
    const float* __restrict__ beta, double* __restrict__ out,
    float* __restrict__ out32, int mode)
{
    __shared__ double As[64][130];
    __shared__ double Ws[64][130];
    const int m0 = blockIdx.x * 64;
    const int j0 = blockIdx.y * 64;
    for (int e = threadIdx.x; e < 64 * 128; e += 256) {
        int r = e >> 7, c = e & 127;
        As[r][c] = A[(size_t)(m0 + r) * 128 + c];
        int j = j0 + r;
        double wv;
        if (mode == 0) wv = (j < 128) ? (double)W[j * 256 + c] : (double)W[(j - 128) * 256 + 128 + c];
        else           wv = (double)W[j * 128 + c];
        Ws[r][c] = wv;
    }
    __syncthreads();
    const int ri = threadIdx.x >> 4, ci = threadIdx.x & 15;
    double acc[4][4];
#pragma unroll
    for (int u = 0; u < 4; ++u)
#pragma unroll
        for (int v = 0; v < 4; ++v) acc[u][v] = 0.0;
    for (int c = 0; c < 128; c += 2) {
        double a0[4], a1[4], w0[4], w1[4];
#pragma unroll
        for (int u = 0; u < 4; ++u) { a0[u] = As[ri + 16 * u][c]; a1[u] = As[ri + 16 * u][c + 1]; }
#pragma unroll
        for (int v = 0; v < 4; ++v) { w0[v] = Ws[ci + 16 * v][c]; w1[v] = Ws[ci + 16 * v][c + 1]; }
#pragma unroll
        for (int u = 0; u < 4; ++u)
#pragma unroll
            for (int v = 0; v < 4; ++v)
                acc[u][v] = fma(a1[u], w1[v], fma(a0[u], w0[v], acc[u][v]));
    }
#pragma unroll
    for (int u = 0; u < 4; ++u) {
        int row = m0 + ri + 16 * u;
#pragma unroll
        for (int v = 0; v < 4; ++v) {
            int jl = ci + 16 * v;
            double val = acc[u][v];
            if (mode == 0) {
                out[(size_t)row * 256 + j0 + jl] = val;
            } else {
                int jg = j0 + jl;
                double z = (val + (double)bias[jg]) * (double)gamma[jg] + (double)beta[jg];
                if (mode == 1) {
                    out[(size_t)row * 128 + jg] = gelu64(z);
                } else {
                    out[(size_t)row * 128 + jg] = z;
                    out32[(size_t)row * 128 + jg] = (float)z;
                }
            }
        }
    }
}

// ---------------- combine64 (in-place residual): xt += max_k gelu((G1+b-G2_i+G2_j)*gamma+beta)
__global__ __launch_bounds__(256) void combine64_kernel(
    double* __restrict__ xt, const double* __restrict__ G,
    const int* __restrict__ idx, const float* __restrict__ bias,
    const float* __restrict__ gamma, const float* __restrict__ beta)
{
    const int row = blockIdx.x * 2 + (threadIdx.x >> 7);
    const int o = threadIdx.x & 127;
    const int b = row >> 11;
    const double* Gb = G + (size_t)(b * 2048) * 256;
    const int* id9 = idx + (size_t)row * 9;
    double g1  = G[(size_t)row * 256 + o];
    double g2i = G[(size_t)row * 256 + 128 + o];
    double base = g1 + (double)bias[o] - g2i;
    double gm = (double)gamma[o], bt = (double)beta[o];
    double mx = -1.0e300;
#pragma unroll
    for (int k = 0; k < 9; ++k) {
        int j = id9[k];
        double h = base + Gb[(size_t)j * 256 + 128 + o];
        double z = h * gm + bt;
        mx = fmax(mx, gelu64(z));
    }
    xt[(size_t)row * 128 + o] += mx;
}

// ---------------- f32 GEMM (block-2 value path). modes as gemm64
__global__ __launch_bounds__(256) void gemm128_kernel(
    const float* __restrict__ A, const float* __restrict__ W,
    const float* __restrict__ bias, const float* __restrict__ gamma,
    const float* __restrict__ beta, float* __restrict__ out, int mode)
{
    __shared__ float Al[128][132];
    __shared__ float Wl[128][132];
    const int m0 = blockIdx.x * 128;
    const int j0 = blockIdx.y * 128;
    for (int e = threadIdx.x; e < 128 * 32; e += 256) {
        int r = e >> 5, q = e & 31;
        *(float4*)&Al[r][q * 4] = *(const float4*)(A + (size_t)(m0 + r) * 128 + q * 4);
    }
    for (int e = threadIdx.x; e < 128 * 32; e += 256) {
        int jj = e >> 5, q = e & 31;
        int c = q * 4;
        const float* src;
        if (mode == 0) {
            int j = j0 + jj;
            src = (j < 128) ? (W + j * 256 + c) : (W + (j - 128) * 256 + 128 + c);
        } else {
            src = W + jj * 128 + c;
        }
        *(float4*)&Wl[jj][c] = *(const float4*)src;
    }
    __syncthreads();
    const int ri = threadIdx.x >> 4, ci = threadIdx.x & 15;
    float acc[8][8];
#pragma unroll
    for (int u = 0; u < 8; ++u)
#pragma unroll
        for (int v = 0; v < 8; ++v) acc[u][v] = 0.0f;
    for (int c = 0; c < 128; c += 4) {
        float4 a4[8];
#pragma unroll
        for (int u = 0; u < 8; ++u) a4[u] = *(const float4*)&Al[ri + 16 * u][c];
#pragma unroll
        for (int v = 0; v < 8; ++v) {
            float4 w4 = *(const float4*)&Wl[ci + 16 * v][c];
#pragma unroll
            for (int u = 0; u < 8; ++u) {
                acc[u][v] = fmaf(a4[u].x, w4.x, fmaf(a4[u].y, w4.y,
                            fmaf(a4[u].z, w4.z, fmaf(a4[u].w, w4.w, acc[u][v]))));
            }
        }
    }
#pragma unroll
    for (int u = 0; u < 8; ++u) {
        int row = m0 + ri + 16 * u;
#pragma unroll
        for (int v = 0; v < 8; ++v) {
            int j = ci + 16 * v;
            float val = acc[u][v];
            if (mode == 0) {
                out[(size_t)row * 256 + j0 + j] = val;
            } else if (mode == 1) {
                float z = (val + bias[j]) * gamma[j] + beta[j];
                out[(size_t)row * 128 + j] = gelu_exact(z);
            } else {
                float z = (val + bias[j]) * gamma[j] + beta[j];
                out[(size_t)row * 128 + j] = z;
            }
        }
    }
}

// ---------------- combine f32 (block 2; in-place safe: reads only own row of xt)
__global__ __launch_bounds__(256) void combine_kernel(
    const float* __restrict__ xt, const float* __restrict__ G,
    const int* __restrict__ idx, const float* __restrict__ bias,
    const float* __restrict__ gamma, const float* __restrict__ beta,
    float* __restrict__ xt2)
{
    const int row = blockIdx.x * 2 + (threadIdx.x >> 7);
    const int o = threadIdx.x & 127;
    const int b = row >> 11;
    const float* Gb = G + (size_t)(b * 2048) * 256;
    const int* id9 = idx + (size_t)row * 9;
    float g1  = G[(size_t)row * 256 + o];
    float g2i = G[(size_t)row * 256 + 128 + o];
    float base = g1 + bias[o] - g2i;
    float gm = gamma[o], bt = beta[o];
    float mx = -3.4e38f;
#pragma unroll
    for (int k = 0; k < 9; ++k) {
        int j = id9[k];
        float h = base + Gb[(size_t)j * 256 + 128 + o];
        float z = h * gm + bt;
        mx = fmaxf(mx, gelu_exact(z));
    }
    xt2[(size_t)row * 128 + o] = xt[(size_t)row * 128 + o] + mx;
}

extern "C" void kernel_launch(void* const* d_in, const int* in_sizes, int n_in,
                              void* d_out, int out_size, void* d_ws, size_t ws_size,
                              hipStream_t stream)
{
    const float* ts       = (const float*)d_in[0];
    const float* conv1_w  = (const float*)d_in[1];
    const float* conv1_b  = (const float*)d_in[2];
    const float* conv2_w  = (const float*)d_in[3];
    const float* conv2_b  = (const float*)d_in[4];
    const float* gconv_w  = (const float*)d_in[5];
    const float* gconv_b  = (const float*)d_in[6];
    const float* gconv_g  = (const float*)d_in[7];
    const float* gconv_be = (const float*)d_in[8];
    const float* ffn1_w   = (const float*)d_in[9];
    const float* ffn1_b   = (const float*)d_in[10];
    const float* ffn1_g   = (const float*)d_in[11];
    const float* ffn1_be  = (const float*)d_in[12];
    const float* ffn2_w   = (const float*)d_in[13];
    const float* ffn2_b   = (const float*)d_in[14];
    const float* ffn2_g   = (const float*)d_in[15];
    const float* ffn2_be  = (const float*)d_in[16];
    (void)in_sizes; (void)n_in; (void)out_size; (void)ws_size;

    // ---- workspace layout (byte offsets), lifetime-overlaid; peak ~102 MB ----
    char* base = (char*)d_ws;
    double* XT64  = (double*)(base + 0);            // 33.55 MB
    double* H1_64 = (double*)(base + 33554432);     // 16.78 MB (conv phase only)
    float*  XN32  = (float*) (base + 33554432);     // 16.78 MB (norm -> stage1)
    int*    CAND  = (int*)   (base + 50331648);     // 2.10 MB  (stage1 -> rescore)
    double* G64   = (double*)(base + 33554432);     // 67.11 MB (gemm0 -> combine, blk1)
    double* H64   = (double*)(base + 33554432);     // 33.55 MB (ffn1 -> ffn2, blk1)
    float*  XT32P = (float*) (base + 67108864);     // 16.78 MB (blk1 ffn2 -> blk2 value path)
    int*    IDX   = (int*)   (base + 100663296);    // 1.18 MB  (rescore -> combine)
    float*  G32   = (float*) (base + 33554432);     // 33.55 MB (blk2)
    float*  H32   = (float*) (base + 33554432);     // 16.78 MB (blk2 ffn)

    float* fout = (float*)d_out;

    conv1_kernel64<<<dim3(64, 16), 256, 0, stream>>>(ts, conv1_w, conv1_b, H1_64);
    conv2_kernel64<<<dim3(64, 16), 256, 0, stream>>>(H1_64, conv2_w, conv2_b, XT64);

    // ---------- block 1 (f64 value path; indices exact) ----------
    norm32_kernel<<<8192, 256, 0, stream>>>(XT64, XN32);
    knn_mfma_kernel<<<dim3(32, 16), 256, 0, stream>>>(XN32, CAND);
    rescore_kernel<<<8192, 256, 0, stream>>>(XT64, CAND, IDX);
    gemm64_kernel<<<dim3(512, 4), 256, 0, stream>>>(
        XT64, gconv_w, nullptr, nullptr, nullptr, G64, nullptr, 0);
    combine64_kernel<<<16384, 256, 0, stream>>>(
        XT64, G64, IDX, gconv_b, gconv_g, gconv_be);
    gemm64_kernel<<<dim3(512, 2), 256, 0, stream>>>(
        XT64, ffn1_w, ffn1_b, ffn1_g, ffn1_be, H64, nullptr, 1);
    gemm64_kernel<<<dim3(512, 2), 256, 0, stream>>>(
        H64, ffn2_w, ffn2_b, ffn2_g, ffn2_be, XT64, XT32P, 2);

    // ---------- block 2 (indices exact via f64; value path f32) ----------
    norm32_kernel<<<8192, 256, 0, stream>>>(XT64, XN32);
    knn_mfma_kernel<<<dim3(32, 16), 256, 0, stream>>>(XN32, CAND);
    rescore_kernel<<<8192, 256, 0, stream>>>(XT64, CAND, IDX);
    gemm128_kernel<<<dim3(256, 2), 256, 0, stream>>>(
        XT32P, gconv_w + 32768, nullptr, nullptr, nullptr, G32, 0);
    combine_kernel<<<16384, 256, 0, stream>>>(
        XT32P, G32, IDX, gconv_b + 128, gconv_g + 128, gconv_be + 128, XT32P);
    gemm128_kernel<<<dim3(256, 1), 256, 0, stream>>>(
        XT32P, ffn1_w + 16384, ffn1_b + 128, ffn1_g + 128, ffn1_be + 128, H32, 1);
    gemm128_kernel<<<dim3(256, 1), 256, 0, stream>>>(
        H32, ffn2_w + 16384, ffn2_b + 128, ffn2_g + 128, ffn2_be + 128, fout, 2);
}

// Round 5
// 1767.984 us; speedup vs baseline: 1.6358x; 1.6358x over previous
//
#include <hip/hip_runtime.h>
#include <hip/hip_bf16.h>

#define DEV_INLINE __device__ __forceinline__

typedef short s16x8 __attribute__((ext_vector_type(8)));
typedef float f32x4 __attribute__((ext_vector_type(4)));

DEV_INLINE float gelu_exact(float x) {
    return 0.5f * x * (1.0f + erff(x * 0.70710678118654752440f));
}
DEV_INLINE double gelu64(double x) {
    return 0.5 * x * (1.0 + erf(x * 0.70710678118654752440));
}
DEV_INLINE unsigned short f2bf_rne(float f) {
    unsigned u = __float_as_uint(f);
    unsigned r = u + 0x7FFFu + ((u >> 16) & 1u);
    return (unsigned short)(r >> 16);
}
DEV_INLINE float bf2f(unsigned short h) { return __uint_as_float(((unsigned)h) << 16); }

// ---------------- conv1 (f64): ts (16,100,2048) f32 -> relu(causal conv d=1) -> h1 (16,64,2048) f64
__global__ __launch_bounds__(256) void conv1_kernel64(
    const float* __restrict__ x, const float* __restrict__ w,
    const float* __restrict__ bias, double* __restrict__ y)
{
    const int b = blockIdx.y;
    const int t0 = blockIdx.x * 32;
    __shared__ double xs[100][34];
    for (int e = threadIdx.x; e < 100 * 34; e += 256) {
        int i = e / 34, u = e - i * 34;
        int t = t0 - 2 + u;
        xs[i][u] = (t >= 0) ? (double)x[(b * 100 + i) * 2048 + t] : 0.0;
    }
    __syncthreads();
    const int o = threadIdx.x & 63;
    const int ts = (threadIdx.x >> 6) * 8;
    double acc[8];
    double bv = (double)bias[o];
#pragma unroll
    for (int j = 0; j < 8; ++j) acc[j] = bv;
    const float* wo = w + o * 300;
    for (int i = 0; i < 100; ++i) {
        double w0 = (double)wo[i * 3 + 0], w1 = (double)wo[i * 3 + 1], w2 = (double)wo[i * 3 + 2];
#pragma unroll
        for (int j = 0; j < 8; ++j) {
            acc[j] = fma(w0, xs[i][ts + j],
                     fma(w1, xs[i][ts + j + 1],
                     fma(w2, xs[i][ts + j + 2], acc[j])));
        }
    }
#pragma unroll
    for (int j = 0; j < 8; ++j)
        y[(b * 64 + o) * 2048 + t0 + ts + j] = fmax(acc[j], 0.0);
}

// ---------------- conv2 (f64): h1 -> relu(causal conv d=2) -> xt64 (16,2048,128) transposed
__global__ __launch_bounds__(256) void conv2_kernel64(
    const double* __restrict__ x, const float* __restrict__ w,
    const float* __restrict__ bias, double* __restrict__ xt)
{
    const int b = blockIdx.y;
    const int t0 = blockIdx.x * 32;
    __shared__ double xs[64][36];
    for (int e = threadIdx.x; e < 64 * 36; e += 256) {
        int i = e / 36, u = e - i * 36;
        int t = t0 - 4 + u;
        xs[i][u] = (t >= 0) ? x[(b * 64 + i) * 2048 + t] : 0.0;
    }
    __syncthreads();
    const int o = threadIdx.x & 127;
    const int ts = (threadIdx.x >> 7) * 16;
    double acc[16];
    double bv = (double)bias[o];
#pragma unroll
    for (int j = 0; j < 16; ++j) acc[j] = bv;
    const float* wo = w + o * 192;
    for (int i = 0; i < 64; ++i) {
        double w0 = (double)wo[i * 3 + 0], w1 = (double)wo[i * 3 + 1], w2 = (double)wo[i * 3 + 2];
#pragma unroll
        for (int j = 0; j < 16; ++j) {
            acc[j] = fma(w0, xs[i][ts + j],
                     fma(w1, xs[i][ts + j + 2],
                     fma(w2, xs[i][ts + j + 4], acc[j])));
        }
    }
#pragma unroll
    for (int j = 0; j < 16; ++j)
        xt[(size_t)(b * 2048 + t0 + ts + j) * 128 + o] = fmax(acc[j], 0.0);
}

// ---------------- norm+split: xt64 -> normalized f32 -> hi/mid bf16 planes (linear layout)
__global__ __launch_bounds__(256) void norm_planes_kernel(
    const double* __restrict__ xt64, unsigned short* __restrict__ XH,
    unsigned short* __restrict__ XM)
{
    const int row = blockIdx.x * 4 + (threadIdx.x >> 6);
    const int lane = threadIdx.x & 63;
    double v0 = xt64[(size_t)row * 128 + lane * 2];
    double v1 = xt64[(size_t)row * 128 + lane * 2 + 1];
    double s = v0 * v0 + v1 * v1;
#pragma unroll
    for (int off = 32; off > 0; off >>= 1) s += __shfl_xor(s, off);
    double inv = 1.0 / fmax(sqrt(s), 1e-12);
    float x0 = (float)(v0 * inv), x1 = (float)(v1 * inv);
    unsigned short h0 = f2bf_rne(x0), h1 = f2bf_rne(x1);
    unsigned short m0 = f2bf_rne(x0 - bf2f(h0)), m1 = f2bf_rne(x1 - bf2f(h1));
    ushort2 hv; hv.x = h0; hv.y = h1;
    ushort2 mv; mv.x = m0; mv.y = m1;
    *(ushort2*)(XH + (size_t)row * 128 + lane * 2) = hv;
    *(ushort2*)(XM + (size_t)row * 128 + lane * 2) = mv;
}

// ---------------- knn stage 1 v2: 4-term bf16 MFMA gram; top-16 candidates per row.
// 512 blocks (XCD-swizzled), 256 thr / 4 waves; 64 A-rows/block (16/wave, regs);
// B: 64-m tiles double-buffered in LDS (2 planes), T14 async staging.
__global__ __launch_bounds__(256, 2) void knn_mfma2_kernel(
    const unsigned short* __restrict__ XH, const unsigned short* __restrict__ XM,
    int* __restrict__ cand_out)
{
    __shared__ __align__(16) unsigned char smem[74240];

    const int tid = threadIdx.x, wave = tid >> 6, lane = tid & 63;
    const int lb = (blockIdx.x & 7) * 64 + (blockIdx.x >> 3);  // XCD swizzle (512%8==0, bijective)
    const int b = lb >> 5, n0 = (lb & 31) * 64;
    const unsigned short* Hb = XH + (size_t)b * 2048 * 128;
    const unsigned short* Mb = XM + (size_t)b * 2048 * 128;

    // A fragments in registers: row = n0 + wave*16 + (lane&15); k-chunk s: cols s*32 + (lane>>4)*8
    s16x8 aH[4], aM[4];
    {
        int arow = n0 + wave * 16 + (lane & 15);
        const unsigned short* hrow = Hb + (size_t)arow * 128;
        const unsigned short* mrow = Mb + (size_t)arow * 128;
        int cb = (lane >> 4) * 8;
#pragma unroll
        for (int s = 0; s < 4; ++s) {
            aH[s] = *(const s16x8*)(hrow + s * 32 + cb);
            aM[s] = *(const s16x8*)(mrow + s * 32 + cb);
        }
    }

    float tv[4][9];
    int   ti[4][9];
#pragma unroll
    for (int q = 0; q < 4; ++q)
#pragma unroll
        for (int t = 0; t < 9; ++t) { tv[q][t] = -3.0e38f; ti[q][t] = 0x3FFFFFFF; }

    // staging unit u = c*256+tid in [0,2048): plane p=u>>10, row r=(u>>4)&63, col16=u&15
    // LDS (swizzled): buf*32768 + p*16384 + r*256 + ((col16*16) ^ ((r&7)<<4))
    // prologue: stage tile 0
    {
        float4 st[8];
#pragma unroll
        for (int c = 0; c < 8; ++c) {
            int u = c * 256 + tid; int p = u >> 10, r = (u >> 4) & 63, col = u & 15;
            const unsigned short* src = (p ? Mb : Hb) + (size_t)r * 128 + col * 8;
            st[c] = *(const float4*)src;
        }
#pragma unroll
        for (int c = 0; c < 8; ++c) {
            int u = c * 256 + tid; int p = u >> 10, r = (u >> 4) & 63, col = u & 15;
            *(float4*)(smem + p * 16384 + r * 256 + ((col * 16) ^ ((r & 7) << 4))) = st[c];
        }
        __syncthreads();
    }

    int cur = 0;
    for (int t = 0; t < 32; ++t) {
        const int m0t = t * 64;
        float4 st[8];
        if (t < 31) {
            int mnext = m0t + 64;
#pragma unroll
            for (int c = 0; c < 8; ++c) {
                int u = c * 256 + tid; int p = u >> 10, r = (u >> 4) & 63, col = u & 15;
                const unsigned short* src = (p ? Mb : Hb) + (size_t)(mnext + r) * 128 + col * 8;
                st[c] = *(const float4*)src;
            }
        }
        // compute tile t from buf[cur]
        const unsigned char* B0 = smem + cur * 32768;
        const unsigned char* B1 = B0 + 16384;
#pragma unroll
        for (int ct = 0; ct < 4; ++ct) {
            f32x4 acc; acc[0] = 0.f; acc[1] = 0.f; acc[2] = 0.f; acc[3] = 0.f;
            int r = ct * 16 + (lane & 15);
#pragma unroll
            for (int s = 0; s < 4; ++s) {
                int off = r * 256 + (((s * 64) + ((lane >> 4) * 16)) ^ ((r & 7) << 4));
                s16x8 bH = *(const s16x8*)(B0 + off);
                s16x8 bM = *(const s16x8*)(B1 + off);
                acc = __builtin_amdgcn_mfma_f32_16x16x32_bf16(aH[s], bH, acc, 0, 0, 0);
                acc = __builtin_amdgcn_mfma_f32_16x16x32_bf16(aH[s], bM, acc, 0, 0, 0);
                acc = __builtin_amdgcn_mfma_f32_16x16x32_bf16(aM[s], bH, acc, 0, 0, 0);
                acc = __builtin_amdgcn_mfma_f32_16x16x32_bf16(aM[s], bM, acc, 0, 0, 0);
            }
            int mg = m0t + ct * 16 + (lane & 15);
#pragma unroll
            for (int q = 0; q < 4; ++q) {
                float candv = acc[q];
                if (candv > tv[q][8]) {   // ascending m + strict '>' keeps lower index on ties
                    tv[q][8] = candv; ti[q][8] = mg;
#pragma unroll
                    for (int u2 = 8; u2 > 0; --u2) {
                        if (tv[q][u2] > tv[q][u2 - 1]) {
                            float tmpv = tv[q][u2]; tv[q][u2] = tv[q][u2 - 1]; tv[q][u2 - 1] = tmpv;
                            int tmpi = ti[q][u2]; ti[q][u2] = ti[q][u2 - 1]; ti[q][u2 - 1] = tmpi;
                        }
                    }
                }
            }
        }
        if (t < 31) {
#pragma unroll
            for (int c = 0; c < 8; ++c) {
                int u = c * 256 + tid; int p = u >> 10, r = (u >> 4) & 63, col = u & 15;
                *(float4*)(smem + (cur ^ 1) * 32768 + p * 16384 + r * 256 +
                           ((col * 16) ^ ((r & 7) << 4))) = st[c];
            }
        }
        __syncthreads();
        cur ^= 1;
    }

    // merge 16 per-lane lists per row -> top-16 candidates (overlay on LDS)
    float* mV = (float*)smem;
    int*   mI = (int*)(smem + 37120);
    {
        int rbase = wave * 16 + (lane >> 4) * 4;
        int slot = lane & 15;
#pragma unroll
        for (int q = 0; q < 4; ++q)
#pragma unroll
            for (int t = 0; t < 9; ++t) {
                mV[(rbase + q) * 145 + slot * 9 + t] = tv[q][t];
                mI[(rbase + q) * 145 + slot * 9 + t] = ti[q][t];
            }
    }
    __syncthreads();
    if (tid < 64) {
        float* V = mV + tid * 145;
        int*   I = mI + tid * 145;
        size_t outbase = ((size_t)(b * 2048) + n0 + tid) * 16;
        for (int pass = 0; pass < 16; ++pass) {
            float best = -3.4e38f; int bi = 1 << 30; int bp = 0;
            for (int j = 0; j < 144; ++j) {
                float v = V[j];
                int id = I[j];
                if (v > best || (v == best && id < bi)) { best = v; bi = id; bp = j; }
            }
            V[bp] = -3.4e38f;
            cand_out[outbase + pass] = bi;
        }
    }
}

// ---------------- knn stage 2 (f64): exact rescore of 16 candidates, pick top-9 (stable ties)
__global__ __launch_bounds__(256) void rescore_kernel(
    const double* __restrict__ xt64, const int* __restrict__ cand, int* __restrict__ idx_out)
{
    const int wid = threadIdx.x >> 6, lane = threadIdx.x & 63;
    const int n = blockIdx.x * 4 + wid;
    const int b = n >> 11;
    const double* Xb = xt64 + (size_t)b * 2048 * 128;
    const double* xr = xt64 + (size_t)n * 128;
    double a0 = xr[lane * 2], a1 = xr[lane * 2 + 1];
    double snn = a0 * a0 + a1 * a1;
#pragma unroll
    for (int off = 32; off > 0; off >>= 1) snn += __shfl_xor(snn, off);
    double invn = 1.0 / fmax(sqrt(snn), 1e-12);
    double sc[16]; int cd[16];
#pragma unroll
    for (int k = 0; k < 16; ++k) {
        int m = cand[(size_t)n * 16 + k];
        const double* xm = Xb + (size_t)m * 128;
        double m0v = xm[lane * 2], m1v = xm[lane * 2 + 1];
        double dnm = a0 * m0v + a1 * m1v;
        double dmm = m0v * m0v + m1v * m1v;
#pragma unroll
        for (int off = 32; off > 0; off >>= 1) {
            dnm += __shfl_xor(dnm, off);
            dmm += __shfl_xor(dmm, off);
        }
        double invm = 1.0 / fmax(sqrt(dmm), 1e-12);
        sc[k] = 2.0 * dnm * invn * invm - dmm * invm * invm;
        cd[k] = m;
    }
    if (lane == 0) {
        unsigned usedmask = 0;
        size_t ob = (size_t)n * 9;
        for (int p = 0; p < 9; ++p) {
            double best = -1.0e300; int bi = 1 << 30; int bp = 0;
#pragma unroll
            for (int j = 0; j < 16; ++j) {
                if (usedmask & (1u << j)) continue;
                if (sc[j] > best || (sc[j] == best && cd[j] < bi)) { best = sc[j]; bi = cd[j]; bp = j; }
            }
            usedmask |= 1u << bp;
            idx_out[ob + p] = bi;
        }
    }
}

// ---------------- f64 GEMM (K=128, staged in 2 chunks of 64 -> 67.6 KB LDS, 2 blocks/CU).
// mode 0: G=Xt@[W1;W2]^T (ld 256); 1: gelu affine; 2: affine (+f32 copy)
__global__ __launch_bounds__(256) void gemm64_kernel(
    const double* __restrict__ A, const float* __restrict__ W,
    const float* __restrict__ bias, const float* __restrict__ gamma,
    const float* __restrict__ beta, double* __restrict__ out,
    float* __restrict__ out32, int mode)
{
    __shared__ double As[64][66];
    __shared__ double Ws[64][66];
    const int m0 = blockIdx.x * 64;
    const int j0 = blockIdx.y * 64;
    const int ri = threadIdx.x >> 4, ci = threadIdx.x & 15;
    double acc[4][4];
#pragma unroll
    for (int u = 0; u < 4; ++u)
#pragma unroll
        for (int v = 0; v < 4; ++v) acc[u][v] = 0.0;

    for (int k0 = 0; k0 < 128; k0 += 64) {
        __syncthreads();
        for (int e = threadIdx.x; e < 64 * 64; e += 256) {
            int r = e >> 6, c = e & 63;
            As[r][c] = A[(size_t)(m0 + r) * 128 + k0 + c];
            int j = j0 + r;
            double wv;
            if (mode == 0) wv = (j < 128) ? (double)W[j * 256 + k0 + c] : (double)W[(j - 128) * 256 + 128 + k0 + c];
            else           wv = (double)W[j * 128 + k0 + c];
            Ws[r][c] = wv;
        }
        __syncthreads();
        for (int c = 0; c < 64; c += 2) {
            double a0[4], a1[4], w0[4], w1[4];
#pragma unroll
            for (int u = 0; u < 4; ++u) { a0[u] = As[ri + 16 * u][c]; a1[u] = As[ri + 16 * u][c + 1]; }
#pragma unroll
            for (int v = 0; v < 4; ++v) { w0[v] = Ws[ci + 16 * v][c]; w1[v] = Ws[ci + 16 * v][c + 1]; }
#pragma unroll
            for (int u = 0; u < 4; ++u)
#pragma unroll
                for (int v = 0; v < 4; ++v)
                    acc[u][v] = fma(a1[u], w1[v], fma(a0[u], w0[v], acc[u][v]));
        }
    }
#pragma unroll
    for (int u = 0; u < 4; ++u) {
        int row = m0 + ri + 16 * u;
#pragma unroll
        for (int v = 0; v < 4; ++v) {
            int jl = ci + 16 * v;
            double val = acc[u][v];
            if (mode == 0) {
                out[(size_t)row * 256 + j0 + jl] = val;
            } else {
                int jg = j0 + jl;
                double z = (val + (double)bias[jg]) * (double)gamma[jg] + (double)beta[jg];
                if (mode == 1) {
                    out[(size_t)row * 128 + jg] = gelu64(z);
                } else {
                    out[(size_t)row * 128 + jg] = z;
                    out32[(size_t)row * 128 + jg] = (float)z;
                }
            }
        }
    }
}

// ---------------- combine64 (in-place residual): xt += max_k gelu((G1+b-G2_i+G2_j)*gamma+beta)
__global__ __launch_bounds__(256) void combine64_kernel(
    double* __restrict__ xt, const double* __restrict__ G,
    const int* __restrict__ idx, const float* __restrict__ bias,
    const float* __restrict__ gamma, const float* __restrict__ beta)
{
    const int row = blockIdx.x * 2 + (threadIdx.x >> 7);
    const int o = threadIdx.x & 127;
    const int b = row >> 11;
    const double* Gb = G + (size_t)(b * 2048) * 256;
    const int* id9 = idx + (size_t)row * 9;
    double g1  = G[(size_t)row * 256 + o];
    double g2i = G[(size_t)row * 256 + 128 + o];
    double base = g1 + (double)bias[o] - g2i;
    double gm = (double)gamma[o], bt = (double)beta[o];
    double mx = -1.0e300;
#pragma unroll
    for (int k = 0; k < 9; ++k) {
        int j = id9[k];
        double h = base + Gb[(size_t)j * 256 + 128 + o];
        double z = h * gm + bt;
        mx = fmax(mx, gelu64(z));
    }
    xt[(size_t)row * 128 + o] += mx;
}

// ---------------- f32 GEMM (block-2 value path). modes as gemm64
__global__ __launch_bounds__(256) void gemm128_kernel(
    const float* __restrict__ A, const float* __restrict__ W,
    const float* __restrict__ bias, const float* __restrict__ gamma,
    const float* __restrict__ beta, float* __restrict__ out, int mode)
{
    __shared__ float Al[128][132];
    __shared__ float Wl[128][132];
    const int m0 = blockIdx.x * 128;
    const int j0 = blockIdx.y * 128;
    for (int e = threadIdx.x; e < 128 * 32; e += 256) {
        int r = e >> 5, q = e & 31;
        *(float4*)&Al[r][q * 4] = *(const float4*)(A + (size_t)(m0 + r) * 128 + q * 4);
    }
    for (int e = threadIdx.x; e < 128 * 32; e += 256) {
        int jj = e >> 5, q = e & 31;
        int c = q * 4;
        const float* src;
        if (mode == 0) {
            int j = j0 + jj;
            src = (j < 128) ? (W + j * 256 + c) : (W + (j - 128) * 256 + 128 + c);
        } else {
            src = W + jj * 128 + c;
        }
        *(float4*)&Wl[jj][c] = *(const float4*)src;
    }
    __syncthreads();
    const int ri = threadIdx.x >> 4, ci = threadIdx.x & 15;
    float acc[8][8];
#pragma unroll
    for (int u = 0; u < 8; ++u)
#pragma unroll
        for (int v = 0; v < 8; ++v) acc[u][v] = 0.0f;
    for (int c = 0; c < 128; c += 4) {
        float4 a4[8];
#pragma unroll
        for (int u = 0; u < 8; ++u) a4[u] = *(const float4*)&Al[ri + 16 * u][c];
#pragma unroll
        for (int v = 0; v < 8; ++v) {
            float4 w4 = *(const float4*)&Wl[ci + 16 * v][c];
#pragma unroll
            for (int u = 0; u < 8; ++u) {
                acc[u][v] = fmaf(a4[u].x, w4.x, fmaf(a4[u].y, w4.y,
                            fmaf(a4[u].z, w4.z, fmaf(a4[u].w, w4.w, acc[u][v]))));
            }
        }
    }
#pragma unroll
    for (int u = 0; u < 8; ++u) {
        int row = m0 + ri + 16 * u;
#pragma unroll
        for (int v = 0; v < 8; ++v) {
            int j = ci + 16 * v;
            float val = acc[u][v];
            if (mode == 0) {
                out[(size_t)row * 256 + j0 + j] = val;
            } else if (mode == 1) {
                float z = (val + bias[j]) * gamma[j] + beta[j];
                out[(size_t)row * 128 + j] = gelu_exact(z);
            } else {
                float z = (val + bias[j]) * gamma[j] + beta[j];
                out[(size_t)row * 128 + j] = z;
            }
        }
    }
}

// ---------------- combine f32 (block 2; in-place safe: reads only own row of xt)
__global__ __launch_bounds__(256) void combine_kernel(
    const float* __restrict__ xt, const float* __restrict__ G,
    const int* __restrict__ idx, const float* __restrict__ bias,
    const float* __restrict__ gamma, const float* __restrict__ beta,
    float* __restrict__ xt2)
{
    const int row = blockIdx.x * 2 + (threadIdx.x >> 7);
    const int o = threadIdx.x & 127;
    const int b = row >> 11;
    const float* Gb = G + (size_t)(b * 2048) * 256;
    const int* id9 = idx + (size_t)row * 9;
    float g1  = G[(size_t)row * 256 + o];
    float g2i = G[(size_t)row * 256 + 128 + o];
    float base = g1 + bias[o] - g2i;
    float gm = gamma[o], bt = beta[o];
    float mx = -3.4e38f;
#pragma unroll
    for (int k = 0; k < 9; ++k) {
        int j = id9[k];
        float h = base + Gb[(size_t)j * 256 + 128 + o];
        float z = h * gm + bt;
        mx = fmaxf(mx, gelu_exact(z));
    }
    xt2[(size_t)row * 128 + o] = xt[(size_t)row * 128 + o] + mx;
}

extern "C" void kernel_launch(void* const* d_in, const int* in_sizes, int n_in,
                              void* d_out, int out_size, void* d_ws, size_t ws_size,
                              hipStream_t stream)
{
    const float* ts       = (const float*)d_in[0];
    const float* conv1_w  = (const float*)d_in[1];
    const float* conv1_b  = (const float*)d_in[2];
    const float* conv2_w  = (const float*)d_in[3];
    const float* conv2_b  = (const float*)d_in[4];
    const float* gconv_w  = (const float*)d_in[5];
    const float* gconv_b  = (const float*)d_in[6];
    const float* gconv_g  = (const float*)d_in[7];
    const float* gconv_be = (const float*)d_in[8];
    const float* ffn1_w   = (const float*)d_in[9];
    const float* ffn1_b   = (const float*)d_in[10];
    const float* ffn1_g   = (const float*)d_in[11];
    const float* ffn1_be  = (const float*)d_in[12];
    const float* ffn2_w   = (const float*)d_in[13];
    const float* ffn2_b   = (const float*)d_in[14];
    const float* ffn2_g   = (const float*)d_in[15];
    const float* ffn2_be  = (const float*)d_in[16];
    (void)in_sizes; (void)n_in; (void)out_size; (void)ws_size;

    // ---- workspace layout (byte offsets), lifetime-overlaid; peak ~102 MB ----
    char* base = (char*)d_ws;
    double*         XT64  = (double*)(base + 0);            // 33.55 MB
    double*         H1_64 = (double*)(base + 33554432);     // 16.78 MB (conv phase only)
    unsigned short* XH    = (unsigned short*)(base + 33554432); // 8.39 MB (norm -> knn)
    unsigned short* XM    = (unsigned short*)(base + 41943040); // 8.39 MB (norm -> knn)
    int*            CAND  = (int*)   (base + 50331648);     // 2.10 MB  (knn -> rescore)
    double*         G64   = (double*)(base + 33554432);     // 67.11 MB (gemm0 -> combine, blk1)
    double*         H64   = (double*)(base + 33554432);     // 33.55 MB (ffn1 -> ffn2, blk1)
    float*          XT32P = (float*) (base + 67108864);     // 16.78 MB (blk1 ffn2 -> blk2 value path)
    int*            IDX   = (int*)   (base + 100663296);    // 1.18 MB  (rescore -> combine)
    float*          G32   = (float*) (base + 33554432);     // 33.55 MB (blk2)
    float*          H32   = (float*) (base + 33554432);     // 16.78 MB (blk2 ffn)

    float* fout = (float*)d_out;

    conv1_kernel64<<<dim3(64, 16), 256, 0, stream>>>(ts, conv1_w, conv1_b, H1_64);
    conv2_kernel64<<<dim3(64, 16), 256, 0, stream>>>(H1_64, conv2_w, conv2_b, XT64);

    // ---------- block 1 (f64 value path; indices exact) ----------
    norm_planes_kernel<<<8192, 256, 0, stream>>>(XT64, XH, XM);
    knn_mfma2_kernel<<<512, 256, 0, stream>>>(XH, XM, CAND);
    rescore_kernel<<<8192, 256, 0, stream>>>(XT64, CAND, IDX);
    gemm64_kernel<<<dim3(512, 4), 256, 0, stream>>>(
        XT64, gconv_w, nullptr, nullptr, nullptr, G64, nullptr, 0);
    combine64_kernel<<<16384, 256, 0, stream>>>(
        XT64, G64, IDX, gconv_b, gconv_g, gconv_be);
    gemm64_kernel<<<dim3(512, 2), 256, 0, stream>>>(
        XT64, ffn1_w, ffn1_b, ffn1_g, ffn1_be, H64, nullptr, 1);
    gemm64_kernel<<<dim3(512, 2), 256, 0, stream>>>(
        H64, ffn2_w, ffn2_b, ffn2_g, ffn2_be, XT64, XT32P, 2);

    // ---------- block 2 (indices exact via f64; value path f32) ----------
    norm_planes_kernel<<<8192, 256, 0, stream>>>(XT64, XH, XM);
    knn_mfma2_kernel<<<512, 256, 0, stream>>>(XH, XM, CAND);
    rescore_kernel<<<8192, 256, 0, stream>>>(XT64, CAND, IDX);
    gemm128_kernel<<<dim3(256, 2), 256, 0, stream>>>(
        XT32P, gconv_w + 32768, nullptr, nullptr, nullptr, G32, 0);
    combine_kernel<<<16384, 256, 0, stream>>>(
        XT32P, G32, IDX, gconv_b + 128, gconv_g + 128, gconv_be + 128, XT32P);
    gemm128_kernel<<<dim3(256, 1), 256, 0, stream>>>(
        XT32P, ffn1_w + 16384, ffn1_b + 128, ffn1_g + 128, ffn1_be + 128, H32, 1);
    gemm128_kernel<<<dim3(256, 1), 256, 0, stream>>>(
        H32, ffn2_w + 16384, ffn2_b + 128, ffn2_g + 128, ffn2_be + 128, fout, 2);
}

// Round 6
// 1454.417 us; speedup vs baseline: 1.9885x; 1.2156x over previous
//
#include <hip/hip_runtime.h>
#include <hip/hip_bf16.h>

#define DEV_INLINE __device__ __forceinline__

typedef short s16x8 __attribute__((ext_vector_type(8)));
typedef float f32x4 __attribute__((ext_vector_type(4)));

DEV_INLINE float gelu_exact(float x) {
    return 0.5f * x * (1.0f + erff(x * 0.70710678118654752440f));
}
DEV_INLINE double gelu64(double x) {
    return 0.5 * x * (1.0 + erf(x * 0.70710678118654752440));
}
DEV_INLINE unsigned short f2bf_rne(float f) {
    unsigned u = __float_as_uint(f);
    unsigned r = u + 0x7FFFu + ((u >> 16) & 1u);
    return (unsigned short)(r >> 16);
}
DEV_INLINE float bf2f(unsigned short h) { return __uint_as_float(((unsigned)h) << 16); }

DEV_INLINE void gload_lds16(const void* g, void* l) {
    __builtin_amdgcn_global_load_lds(
        (const __attribute__((address_space(1))) unsigned int*)g,
        (__attribute__((address_space(3))) unsigned int*)l, 16, 0, 0);
}

// ---------------- conv1 (f64): ts (16,100,2048) f32 -> relu(causal conv d=1) -> h1 (16,64,2048) f64
__global__ __launch_bounds__(256) void conv1_kernel64(
    const float* __restrict__ x, const float* __restrict__ w,
    const float* __restrict__ bias, double* __restrict__ y)
{
    const int b = blockIdx.y;
    const int t0 = blockIdx.x * 32;
    __shared__ double xs[100][34];
    for (int e = threadIdx.x; e < 100 * 34; e += 256) {
        int i = e / 34, u = e - i * 34;
        int t = t0 - 2 + u;
        xs[i][u] = (t >= 0) ? (double)x[(b * 100 + i) * 2048 + t] : 0.0;
    }
    __syncthreads();
    const int o = threadIdx.x & 63;
    const int ts = (threadIdx.x >> 6) * 8;
    double acc[8];
    double bv = (double)bias[o];
#pragma unroll
    for (int j = 0; j < 8; ++j) acc[j] = bv;
    const float* wo = w + o * 300;
    for (int i = 0; i < 100; ++i) {
        double w0 = (double)wo[i * 3 + 0], w1 = (double)wo[i * 3 + 1], w2 = (double)wo[i * 3 + 2];
#pragma unroll
        for (int j = 0; j < 8; ++j) {
            acc[j] = fma(w0, xs[i][ts + j],
                     fma(w1, xs[i][ts + j + 1],
                     fma(w2, xs[i][ts + j + 2], acc[j])));
        }
    }
#pragma unroll
    for (int j = 0; j < 8; ++j)
        y[(b * 64 + o) * 2048 + t0 + ts + j] = fmax(acc[j], 0.0);
}

// ---------------- conv2 (f64): h1 -> relu(causal conv d=2) -> xt64 (16,2048,128) transposed
__global__ __launch_bounds__(256) void conv2_kernel64(
    const double* __restrict__ x, const float* __restrict__ w,
    const float* __restrict__ bias, double* __restrict__ xt)
{
    const int b = blockIdx.y;
    const int t0 = blockIdx.x * 32;
    __shared__ double xs[64][36];
    for (int e = threadIdx.x; e < 64 * 36; e += 256) {
        int i = e / 36, u = e - i * 36;
        int t = t0 - 4 + u;
        xs[i][u] = (t >= 0) ? x[(b * 64 + i) * 2048 + t] : 0.0;
    }
    __syncthreads();
    const int o = threadIdx.x & 127;
    const int ts = (threadIdx.x >> 7) * 16;
    double acc[16];
    double bv = (double)bias[o];
#pragma unroll
    for (int j = 0; j < 16; ++j) acc[j] = bv;
    const float* wo = w + o * 192;
    for (int i = 0; i < 64; ++i) {
        double w0 = (double)wo[i * 3 + 0], w1 = (double)wo[i * 3 + 1], w2 = (double)wo[i * 3 + 2];
#pragma unroll
        for (int j = 0; j < 16; ++j) {
            acc[j] = fma(w0, xs[i][ts + j],
                     fma(w1, xs[i][ts + j + 2],
                     fma(w2, xs[i][ts + j + 4], acc[j])));
        }
    }
#pragma unroll
    for (int j = 0; j < 16; ++j)
        xt[(size_t)(b * 2048 + t0 + ts + j) * 128 + o] = fmax(acc[j], 0.0);
}

// ---------------- norm+split: xt64 -> normalized f32 -> hi/mid bf16 planes (linear layout)
__global__ __launch_bounds__(256) void norm_planes_kernel(
    const double* __restrict__ xt64, unsigned short* __restrict__ XH,
    unsigned short* __restrict__ XM)
{
    const int row = blockIdx.x * 4 + (threadIdx.x >> 6);
    const int lane = threadIdx.x & 63;
    double v0 = xt64[(size_t)row * 128 + lane * 2];
    double v1 = xt64[(size_t)row * 128 + lane * 2 + 1];
    double s = v0 * v0 + v1 * v1;
#pragma unroll
    for (int off = 32; off > 0; off >>= 1) s += __shfl_xor(s, off);
    double inv = 1.0 / fmax(sqrt(s), 1e-12);
    float x0 = (float)(v0 * inv), x1 = (float)(v1 * inv);
    unsigned short h0 = f2bf_rne(x0), h1 = f2bf_rne(x1);
    unsigned short m0 = f2bf_rne(x0 - bf2f(h0)), m1 = f2bf_rne(x1 - bf2f(h1));
    ushort2 hv; hv.x = h0; hv.y = h1;
    ushort2 mv; mv.x = m0; mv.y = m1;
    *(ushort2*)(XH + (size_t)row * 128 + lane * 2) = hv;
    *(ushort2*)(XM + (size_t)row * 128 + lane * 2) = mv;
}

// ---------------- knn stage 1 v3: 4-term bf16 MFMA gram; top-16 candidates per row.
// 256 blocks (1/CU, XCD-swizzled: one batch per XCD-pair slot), 512 thr / 8 waves;
// 128 A-rows/block (16/wave, in regs); B: 64-row tiles double-buffered in LDS via
// global_load_lds (linear dest, inverse-swizzled source, swizzled ds_read).
__global__ __launch_bounds__(512, 2) void knn_mfma3_kernel(
    const unsigned short* __restrict__ XH, const unsigned short* __restrict__ XM,
    int* __restrict__ cand_out)
{
    __shared__ __align__(16) unsigned char smem[65536];  // 2 x 32KB (dbuf: 2 planes x 16KB)

    const int tid = threadIdx.x, wave = tid >> 6, lane = tid & 63;
    // block mapping: xcd = bid&7; j = bid>>3; batch = xcd*2 + (j>>4); ntile = j&15
    const int bid = blockIdx.x;
    const int b = (bid & 7) * 2 + ((bid >> 3) >> 4);
    const int n0 = ((bid >> 3) & 15) * 128;
    const unsigned short* Hb = XH + (size_t)b * 2048 * 128;
    const unsigned short* Mb = XM + (size_t)b * 2048 * 128;

    // A fragments in registers: row = n0 + wave*16 + (lane&15); k-chunk s: cols s*32 + (lane>>4)*8
    s16x8 aH[4], aM[4];
    {
        int arow = n0 + wave * 16 + (lane & 15);
        const unsigned short* hrow = Hb + (size_t)arow * 128;
        const unsigned short* mrow = Mb + (size_t)arow * 128;
        int cb = (lane >> 4) * 8;
#pragma unroll
        for (int s = 0; s < 4; ++s) {
            aH[s] = *(const s16x8*)(hrow + s * 32 + cb);
            aM[s] = *(const s16x8*)(mrow + s * 32 + cb);
        }
    }

    // staging descriptors (gload_lds): plane p = wave>>2 (uniform per wave);
    // c in 0..3: r = (wave&3)*16 + c*4 + (lane>>4); col = (lane&15) ^ (r&7)  [inverse swizzle]
    // LDS dest (wave-uniform) = buf*32768 + (wave*4+c)*1024 ; HW adds lane*16.
    const unsigned short* Pb = (wave >> 2) ? Mb : Hb;
    const unsigned short* gsrc0; const unsigned short* gsrc1;
    const unsigned short* gsrc2; const unsigned short* gsrc3;
    {
        int r0 = (wave & 3) * 16 + 0 + (lane >> 4), c0 = (lane & 15) ^ (r0 & 7);
        int r1 = (wave & 3) * 16 + 4 + (lane >> 4), c1 = (lane & 15) ^ (r1 & 7);
        int r2 = (wave & 3) * 16 + 8 + (lane >> 4), c2 = (lane & 15) ^ (r2 & 7);
        int r3 = (wave & 3) * 16 + 12 + (lane >> 4), c3 = (lane & 15) ^ (r3 & 7);
        gsrc0 = Pb + (size_t)r0 * 128 + c0 * 8;
        gsrc1 = Pb + (size_t)r1 * 128 + c1 * 8;
        gsrc2 = Pb + (size_t)r2 * 128 + c2 * 8;
        gsrc3 = Pb + (size_t)r3 * 128 + c3 * 8;
    }
    const unsigned ldsbase = (wave * 4) * 1024;

    float tv[4][9];
    int   ti[4][9];
#pragma unroll
    for (int q = 0; q < 4; ++q)
#pragma unroll
        for (int t = 0; t < 9; ++t) { tv[q][t] = -3.0e38f; ti[q][t] = 0x3FFFFFFF; }

    // prologue: stage tile 0 into buf 0
    gload_lds16(gsrc0, smem + ldsbase);
    gload_lds16(gsrc1, smem + ldsbase + 1024);
    gload_lds16(gsrc2, smem + ldsbase + 2048);
    gload_lds16(gsrc3, smem + ldsbase + 3072);
    __syncthreads();

    int cur = 0;
    for (int t = 0; t < 32; ++t) {
        const int m0t = t * 64;
        if (t < 31) {  // stage tile t+1 into buf cur^1 (overlaps compute below)
            size_t go = (size_t)(m0t + 64) * 128;
            unsigned lb = (cur ^ 1) * 32768 + ldsbase;
            gload_lds16(gsrc0 + go, smem + lb);
            gload_lds16(gsrc1 + go, smem + lb + 1024);
            gload_lds16(gsrc2 + go, smem + lb + 2048);
            gload_lds16(gsrc3 + go, smem + lb + 3072);
        }
        // compute tile t from buf[cur]
        const unsigned char* B0 = smem + cur * 32768;
        const unsigned char* B1 = B0 + 16384;
#pragma unroll
        for (int ct = 0; ct < 4; ++ct) {
            f32x4 acc; acc[0] = 0.f; acc[1] = 0.f; acc[2] = 0.f; acc[3] = 0.f;
            int r = ct * 16 + (lane & 15);
#pragma unroll
            for (int s = 0; s < 4; ++s) {
                int off = r * 256 + (((s * 64) + ((lane >> 4) * 16)) ^ ((r & 7) << 4));
                s16x8 bH = *(const s16x8*)(B0 + off);
                s16x8 bM = *(const s16x8*)(B1 + off);
                acc = __builtin_amdgcn_mfma_f32_16x16x32_bf16(aH[s], bH, acc, 0, 0, 0);
                acc = __builtin_amdgcn_mfma_f32_16x16x32_bf16(aH[s], bM, acc, 0, 0, 0);
                acc = __builtin_amdgcn_mfma_f32_16x16x32_bf16(aM[s], bH, acc, 0, 0, 0);
                acc = __builtin_amdgcn_mfma_f32_16x16x32_bf16(aM[s], bM, acc, 0, 0, 0);
            }
            int mg = m0t + ct * 16 + (lane & 15);
#pragma unroll
            for (int q = 0; q < 4; ++q) {
                float candv = acc[q];
                if (candv > tv[q][8]) {   // ascending m + strict '>' keeps lower index on ties
                    tv[q][8] = candv; ti[q][8] = mg;
#pragma unroll
                    for (int u2 = 8; u2 > 0; --u2) {
                        if (tv[q][u2] > tv[q][u2 - 1]) {
                            float tmpv = tv[q][u2]; tv[q][u2] = tv[q][u2 - 1]; tv[q][u2 - 1] = tmpv;
                            int tmpi = ti[q][u2]; ti[q][u2] = ti[q][u2 - 1]; ti[q][u2 - 1] = tmpi;
                        }
                    }
                }
            }
        }
        __syncthreads();   // drains vmcnt (t+1 staged) + releases buf[cur] for overwrite
        cur ^= 1;
    }

    // register-resident merge: per q, the 16 lanes of group g=(lane>>4) hold row
    // (wave*16 + g*4 + q)'s sorted top-9 lists; 16 passes of 4-step butterfly max
    // with (value desc, index asc) ordering — identical semantics to serial scan.
    const int slot = lane & 15;
#pragma unroll
    for (int q = 0; q < 4; ++q) {
        int wsel = 0;
#pragma unroll
        for (int pass = 0; pass < 16; ++pass) {
            float hv = tv[q][0]; int hi = ti[q][0];
            float rv = hv; int ri = hi;
#pragma unroll
            for (int s = 1; s < 16; s <<= 1) {
                float ov = __shfl_xor(rv, s);
                int oi = __shfl_xor(ri, s);
                bool take = (ov > rv) || (ov == rv && oi < ri);
                rv = take ? ov : rv;
                ri = take ? oi : ri;
            }
            if (slot == pass) wsel = ri;
            bool won = (hi == ri);  // candidate indices are unique across the group
            if (won) {
#pragma unroll
                for (int u2 = 0; u2 < 8; ++u2) { tv[q][u2] = tv[q][u2 + 1]; ti[q][u2] = ti[q][u2 + 1]; }
                tv[q][8] = -3.4e38f; ti[q][8] = 0x7FFFFFFF;
            }
        }
        int row = b * 2048 + n0 + wave * 16 + (lane >> 4) * 4 + q;
        cand_out[(size_t)row * 16 + slot] = wsel;
    }
}

// ---------------- knn stage 2 (f64): exact rescore of 16 candidates, pick top-9 (stable ties)
__global__ __launch_bounds__(256) void rescore_kernel(
    const double* __restrict__ xt64, const int* __restrict__ cand, int* __restrict__ idx_out)
{
    const int wid = threadIdx.x >> 6, lane = threadIdx.x & 63;
    const int n = blockIdx.x * 4 + wid;
    const int b = n >> 11;
    const double* Xb = xt64 + (size_t)b * 2048 * 128;
    const double* xr = xt64 + (size_t)n * 128;
    double a0 = xr[lane * 2], a1 = xr[lane * 2 + 1];
    double snn = a0 * a0 + a1 * a1;
#pragma unroll
    for (int off = 32; off > 0; off >>= 1) snn += __shfl_xor(snn, off);
    double invn = 1.0 / fmax(sqrt(snn), 1e-12);
    double sc[16]; int cd[16];
#pragma unroll
    for (int k = 0; k < 16; ++k) {
        int m = cand[(size_t)n * 16 + k];
        const double* xm = Xb + (size_t)m * 128;
        double m0v = xm[lane * 2], m1v = xm[lane * 2 + 1];
        double dnm = a0 * m0v + a1 * m1v;
        double dmm = m0v * m0v + m1v * m1v;
#pragma unroll
        for (int off = 32; off > 0; off >>= 1) {
            dnm += __shfl_xor(dnm, off);
            dmm += __shfl_xor(dmm, off);
        }
        double invm = 1.0 / fmax(sqrt(dmm), 1e-12);
        sc[k] = 2.0 * dnm * invn * invm - dmm * invm * invm;
        cd[k] = m;
    }
    if (lane == 0) {
        unsigned usedmask = 0;
        size_t ob = (size_t)n * 9;
        for (int p = 0; p < 9; ++p) {
            double best = -1.0e300; int bi = 1 << 30; int bp = 0;
#pragma unroll
            for (int j = 0; j < 16; ++j) {
                if (usedmask & (1u << j)) continue;
                if (sc[j] > best || (sc[j] == best && cd[j] < bi)) { best = sc[j]; bi = cd[j]; bp = j; }
            }
            usedmask |= 1u << bp;
            idx_out[ob + p] = bi;
        }
    }
}

// ---------------- f64 GEMM (K=128, staged in 2 chunks of 64 -> 67.6 KB LDS, 2 blocks/CU).
// mode 0: G=Xt@[W1;W2]^T (ld 256); 1: gelu affine; 2: affine (+f32 copy)
__global__ __launch_bounds__(256) void gemm64_kernel(
    const double* __restrict__ A, const float* __restrict__ W,
    const float* __restrict__ bias, const float* __restrict__ gamma,
    const float* __restrict__ beta, double* __restrict__ out,
    float* __restrict__ out32, int mode)
{
    __shared__ double As[64][66];
    __shared__ double Ws[64][66];
    const int m0 = blockIdx.x * 64;
    const int j0 = blockIdx.y * 64;
    const int ri = threadIdx.x >> 4, ci = threadIdx.x & 15;
    double acc[4][4];
#pragma unroll
    for (int u = 0; u < 4; ++u)
#pragma unroll
        for (int v = 0; v < 4; ++v) acc[u][v] = 0.0;

    for (int k0 = 0; k0 < 128; k0 += 64) {
        __syncthreads();
        for (int e = threadIdx.x; e < 64 * 64; e += 256) {
            int r = e >> 6, c = e & 63;
            As[r][c] = A[(size_t)(m0 + r) * 128 + k0 + c];
            int j = j0 + r;
            double wv;
            if (mode == 0) wv = (j < 128) ? (double)W[j * 256 + k0 + c] : (double)W[(j - 128) * 256 + 128 + k0 + c];
            else           wv = (double)W[j * 128 + k0 + c];
            Ws[r][c] = wv;
        }
        __syncthreads();
        for (int c = 0; c < 64; c += 2) {
            double a0[4], a1[4], w0[4], w1[4];
#pragma unroll
            for (int u = 0; u < 4; ++u) { a0[u] = As[ri + 16 * u][c]; a1[u] = As[ri + 16 * u][c + 1]; }
#pragma unroll
            for (int v = 0; v < 4; ++v) { w0[v] = Ws[ci + 16 * v][c]; w1[v] = Ws[ci + 16 * v][c + 1]; }
#pragma unroll
            for (int u = 0; u < 4; ++u)
#pragma unroll
                for (int v = 0; v < 4; ++v)
                    acc[u][v] = fma(a1[u], w1[v], fma(a0[u], w0[v], acc[u][v]));
        }
    }
#pragma unroll
    for (int u = 0; u < 4; ++u) {
        int row = m0 + ri + 16 * u;
#pragma unroll
        for (int v = 0; v < 4; ++v) {
            int jl = ci + 16 * v;
            double val = acc[u][v];
            if (mode == 0) {
                out[(size_t)row * 256 + j0 + jl] = val;
            } else {
                int jg = j0 + jl;
                double z = (val + (double)bias[jg]) * (double)gamma[jg] + (double)beta[jg];
                if (mode == 1) {
                    out[(size_t)row * 128 + jg] = gelu64(z);
                } else {
                    out[(size_t)row * 128 + jg] = z;
                    out32[(size_t)row * 128 + jg] = (float)z;
                }
            }
        }
    }
}

// ---------------- combine64 (in-place residual): xt += max_k gelu((G1+b-G2_i+G2_j)*gamma+beta)
__global__ __launch_bounds__(256) void combine64_kernel(
    double* __restrict__ xt, const double* __restrict__ G,
    const int* __restrict__ idx, const float* __restrict__ bias,
    const float* __restrict__ gamma, const float* __restrict__ beta)
{
    const int row = blockIdx.x * 2 + (threadIdx.x >> 7);
    const int o = threadIdx.x & 127;
    const int b = row >> 11;
    const double* Gb = G + (size_t)(b * 2048) * 256;
    const int* id9 = idx + (size_t)row * 9;
    double g1  = G[(size_t)row * 256 + o];
    double g2i = G[(size_t)row * 256 + 128 + o];
    double base = g1 + (double)bias[o] - g2i;
    double gm = (double)gamma[o], bt = (double)beta[o];
    double mx = -1.0e300;
#pragma unroll
    for (int k = 0; k < 9; ++k) {
        int j = id9[k];
        double h = base + Gb[(size_t)j * 256 + 128 + o];
        double z = h * gm + bt;
        mx = fmax(mx, gelu64(z));
    }
    xt[(size_t)row * 128 + o] += mx;
}

// ---------------- f32 GEMM (block-2 value path). modes as gemm64
__global__ __launch_bounds__(256) void gemm128_kernel(
    const float* __restrict__ A, const float* __restrict__ W,
    const float* __restrict__ bias, const float* __restrict__ gamma,
    const float* __restrict__ beta, float* __restrict__ out, int mode)
{
    __shared__ float Al[128][132];
    __shared__ float Wl[128][132];
    const int m0 = blockIdx.x * 128;
    const int j0 = blockIdx.y * 128;
    for (int e = threadIdx.x; e < 128 * 32; e += 256) {
        int r = e >> 5, q = e & 31;
        *(float4*)&Al[r][q * 4] = *(const float4*)(A + (size_t)(m0 + r) * 128 + q * 4);
    }
    for (int e = threadIdx.x; e < 128 * 32; e += 256) {
        int jj = e >> 5, q = e & 31;
        int c = q * 4;
        const float* src;
        if (mode == 0) {
            int j = j0 + jj;
            src = (j < 128) ? (W + j * 256 + c) : (W + (j - 128) * 256 + 128 + c);
        } else {
            src = W + jj * 128 + c;
        }
        *(float4*)&Wl[jj][c] = *(const float4*)src;
    }
    __syncthreads();
    const int ri = threadIdx.x >> 4, ci = threadIdx.x & 15;
    float acc[8][8];
#pragma unroll
    for (int u = 0; u < 8; ++u)
#pragma unroll
        for (int v = 0; v < 8; ++v) acc[u][v] = 0.0f;
    for (int c = 0; c < 128; c += 4) {
        float4 a4[8];
#pragma unroll
        for (int u = 0; u < 8; ++u) a4[u] = *(const float4*)&Al[ri + 16 * u][c];
#pragma unroll
        for (int v = 0; v < 8; ++v) {
            float4 w4 = *(const float4*)&Wl[ci + 16 * v][c];
#pragma unroll
            for (int u = 0; u < 8; ++u) {
                acc[u][v] = fmaf(a4[u].x, w4.x, fmaf(a4[u].y, w4.y,
                            fmaf(a4[u].z, w4.z, fmaf(a4[u].w, w4.w, acc[u][v]))));
            }
        }
    }
#pragma unroll
    for (int u = 0; u < 8; ++u) {
        int row = m0 + ri + 16 * u;
#pragma unroll
        for (int v = 0; v < 8; ++v) {
            int j = ci + 16 * v;
            float val = acc[u][v];
            if (mode == 0) {
                out[(size_t)row * 256 + j0 + j] = val;
            } else if (mode == 1) {
                float z = (val + bias[j]) * gamma[j] + beta[j];
                out[(size_t)row * 128 + j] = gelu_exact(z);
            } else {
                float z = (val + bias[j]) * gamma[j] + beta[j];
                out[(size_t)row * 128 + j] = z;
            }
        }
    }
}

// ---------------- combine f32 (block 2; in-place safe: reads only own row of xt)
__global__ __launch_bounds__(256) void combine_kernel(
    const float* __restrict__ xt, const float* __restrict__ G,
    const int* __restrict__ idx, const float* __restrict__ bias,
    const float* __restrict__ gamma, const float* __restrict__ beta,
    float* __restrict__ xt2)
{
    const int row = blockIdx.x * 2 + (threadIdx.x >> 7);
    const int o = threadIdx.x & 127;
    const int b = row >> 11;
    const float* Gb = G + (size_t)(b * 2048) * 256;
    const int* id9 = idx + (size_t)row * 9;
    float g1  = G[(size_t)row * 256 + o];
    float g2i = G[(size_t)row * 256 + 128 + o];
    float base = g1 + bias[o] - g2i;
    float gm = gamma[o], bt = beta[o];
    float mx = -3.4e38f;
#pragma unroll
    for (int k = 0; k < 9; ++k) {
        int j = id9[k];
        float h = base + Gb[(size_t)j * 256 + 128 + o];
        float z = h * gm + bt;
        mx = fmaxf(mx, gelu_exact(z));
    }
    xt2[(size_t)row * 128 + o] = xt[(size_t)row * 128 + o] + mx;
}

extern "C" void kernel_launch(void* const* d_in, const int* in_sizes, int n_in,
                              void* d_out, int out_size, void* d_ws, size_t ws_size,
                              hipStream_t stream)
{
    const float* ts       = (const float*)d_in[0];
    const float* conv1_w  = (const float*)d_in[1];
    const float* conv1_b  = (const float*)d_in[2];
    const float* conv2_w  = (const float*)d_in[3];
    const float* conv2_b  = (const float*)d_in[4];
    const float* gconv_w  = (const float*)d_in[5];
    const float* gconv_b  = (const float*)d_in[6];
    const float* gconv_g  = (const float*)d_in[7];
    const float* gconv_be = (const float*)d_in[8];
    const float* ffn1_w   = (const float*)d_in[9];
    const float* ffn1_b   = (const float*)d_in[10];
    const float* ffn1_g   = (const float*)d_in[11];
    const float* ffn1_be  = (const float*)d_in[12];
    const float* ffn2_w   = (const float*)d_in[13];
    const float* ffn2_b   = (const float*)d_in[14];
    const float* ffn2_g   = (const float*)d_in[15];
    const float* ffn2_be  = (const float*)d_in[16];
    (void)in_sizes; (void)n_in; (void)out_size; (void)ws_size;

    // ---- workspace layout (byte offsets), lifetime-overlaid; peak ~102 MB ----
    char* base = (char*)d_ws;
    double*         XT64  = (double*)(base + 0);            // 33.55 MB
    double*         H1_64 = (double*)(base + 33554432);     // 16.78 MB (conv phase only)
    unsigned short* XH    = (unsigned short*)(base + 33554432); // 8.39 MB (norm -> knn)
    unsigned short* XM    = (unsigned short*)(base + 41943040); // 8.39 MB (norm -> knn)
    int*            CAND  = (int*)   (base + 50331648);     // 2.10 MB  (knn -> rescore)
    double*         G64   = (double*)(base + 33554432);     // 67.11 MB (gemm0 -> combine, blk1)
    double*         H64   = (double*)(base + 33554432);     // 33.55 MB (ffn1 -> ffn2, blk1)
    float*          XT32P = (float*) (base + 67108864);     // 16.78 MB (blk1 ffn2 -> blk2 value path)
    int*            IDX   = (int*)   (base + 100663296);    // 1.18 MB  (rescore -> combine)
    float*          G32   = (float*) (base + 33554432);     // 33.55 MB (blk2)
    float*          H32   = (float*) (base + 33554432);     // 16.78 MB (blk2 ffn)

    float* fout = (float*)d_out;

    conv1_kernel64<<<dim3(64, 16), 256, 0, stream>>>(ts, conv1_w, conv1_b, H1_64);
    conv2_kernel64<<<dim3(64, 16), 256, 0, stream>>>(H1_64, conv2_w, conv2_b, XT64);

    // ---------- block 1 (f64 value path; indices exact) ----------
    norm_planes_kernel<<<8192, 256, 0, stream>>>(XT64, XH, XM);
    knn_mfma3_kernel<<<256, 512, 0, stream>>>(XH, XM, CAND);
    rescore_kernel<<<8192, 256, 0, stream>>>(XT64, CAND, IDX);
    gemm64_kernel<<<dim3(512, 4), 256, 0, stream>>>(
        XT64, gconv_w, nullptr, nullptr, nullptr, G64, nullptr, 0);
    combine64_kernel<<<16384, 256, 0, stream>>>(
        XT64, G64, IDX, gconv_b, gconv_g, gconv_be);
    gemm64_kernel<<<dim3(512, 2), 256, 0, stream>>>(
        XT64, ffn1_w, ffn1_b, ffn1_g, ffn1_be, H64, nullptr, 1);
    gemm64_kernel<<<dim3(512, 2), 256, 0, stream>>>(
        H64, ffn2_w, ffn2_b, ffn2_g, ffn2_be, XT64, XT32P, 2);

    // ---------- block 2 (indices exact via f64; value path f32) ----------
    norm_planes_kernel<<<8192, 256, 0, stream>>>(XT64, XH, XM);
    knn_mfma3_kernel<<<256, 512, 0, stream>>>(XH, XM, CAND);
    rescore_kernel<<<8192, 256, 0, stream>>>(XT64, CAND, IDX);
    gemm128_kernel<<<dim3(256, 2), 256, 0, stream>>>(
        XT32P, gconv_w + 32768, nullptr, nullptr, nullptr, G32, 0);
    combine_kernel<<<16384, 256, 0, stream>>>(
        XT32P, G32, IDX, gconv_b + 128, gconv_g + 128, gconv_be + 128, XT32P);
    gemm128_kernel<<<dim3(256, 1), 256, 0, stream>>>(
        XT32P, ffn1_w + 16384, ffn1_b + 128, ffn1_g + 128, ffn1_be + 128, H32, 1);
    gemm128_kernel<<<dim3(256, 1), 256, 0, stream>>>(
        H32, ffn2_w + 16384, ffn2_b + 128, ffn2_g + 128, ffn2_be + 128, fout, 2);
}

// Round 7
// 1269.516 us; speedup vs baseline: 2.2781x; 1.1456x over previous
//
#include <hip/hip_runtime.h>
#include <hip/hip_bf16.h>

#define DEV_INLINE __device__ __forceinline__

typedef short s16x8 __attribute__((ext_vector_type(8)));
typedef float f32x4 __attribute__((ext_vector_type(4)));

DEV_INLINE float gelu_exact(float x) {
    return 0.5f * x * (1.0f + erff(x * 0.70710678118654752440f));
}
DEV_INLINE double gelu64(double x) {
    return 0.5 * x * (1.0 + erf(x * 0.70710678118654752440));
}
DEV_INLINE unsigned short f2bf_rne(float f) {
    unsigned u = __float_as_uint(f);
    unsigned r = u + 0x7FFFu + ((u >> 16) & 1u);
    return (unsigned short)(r >> 16);
}
DEV_INLINE float bf2f(unsigned short h) { return __uint_as_float(((unsigned)h) << 16); }

DEV_INLINE void gload_lds16(const void* g, void* l) {
    __builtin_amdgcn_global_load_lds(
        (const __attribute__((address_space(1))) unsigned int*)g,
        (__attribute__((address_space(3))) unsigned int*)l, 16, 0, 0);
}

// ---------------- conv1 (f64): ts (16,100,2048) f32 -> relu(causal conv d=1) -> h1 (16,64,2048) f64
__global__ __launch_bounds__(256) void conv1_kernel64(
    const float* __restrict__ x, const float* __restrict__ w,
    const float* __restrict__ bias, double* __restrict__ y)
{
    const int b = blockIdx.y;
    const int t0 = blockIdx.x * 32;
    __shared__ double xs[100][34];
    for (int e = threadIdx.x; e < 100 * 34; e += 256) {
        int i = e / 34, u = e - i * 34;
        int t = t0 - 2 + u;
        xs[i][u] = (t >= 0) ? (double)x[(b * 100 + i) * 2048 + t] : 0.0;
    }
    __syncthreads();
    const int o = threadIdx.x & 63;
    const int ts = (threadIdx.x >> 6) * 8;
    double acc[8];
    double bv = (double)bias[o];
#pragma unroll
    for (int j = 0; j < 8; ++j) acc[j] = bv;
    const float* wo = w + o * 300;
    for (int i = 0; i < 100; ++i) {
        double w0 = (double)wo[i * 3 + 0], w1 = (double)wo[i * 3 + 1], w2 = (double)wo[i * 3 + 2];
#pragma unroll
        for (int j = 0; j < 8; ++j) {
            acc[j] = fma(w0, xs[i][ts + j],
                     fma(w1, xs[i][ts + j + 1],
                     fma(w2, xs[i][ts + j + 2], acc[j])));
        }
    }
#pragma unroll
    for (int j = 0; j < 8; ++j)
        y[(b * 64 + o) * 2048 + t0 + ts + j] = fmax(acc[j], 0.0);
}

// ---------------- conv2 (f64): h1 -> relu(causal conv d=2) -> xt64 (16,2048,128) transposed
__global__ __launch_bounds__(256) void conv2_kernel64(
    const double* __restrict__ x, const float* __restrict__ w,
    const float* __restrict__ bias, double* __restrict__ xt)
{
    const int b = blockIdx.y;
    const int t0 = blockIdx.x * 32;
    __shared__ double xs[64][36];
    for (int e = threadIdx.x; e < 64 * 36; e += 256) {
        int i = e / 36, u = e - i * 36;
        int t = t0 - 4 + u;
        xs[i][u] = (t >= 0) ? x[(b * 64 + i) * 2048 + t] : 0.0;
    }
    __syncthreads();
    const int o = threadIdx.x & 127;
    const int ts = (threadIdx.x >> 7) * 16;
    double acc[16];
    double bv = (double)bias[o];
#pragma unroll
    for (int j = 0; j < 16; ++j) acc[j] = bv;
    const float* wo = w + o * 192;
    for (int i = 0; i < 64; ++i) {
        double w0 = (double)wo[i * 3 + 0], w1 = (double)wo[i * 3 + 1], w2 = (double)wo[i * 3 + 2];
#pragma unroll
        for (int j = 0; j < 16; ++j) {
            acc[j] = fma(w0, xs[i][ts + j],
                     fma(w1, xs[i][ts + j + 2],
                     fma(w2, xs[i][ts + j + 4], acc[j])));
        }
    }
#pragma unroll
    for (int j = 0; j < 16; ++j)
        xt[(size_t)(b * 2048 + t0 + ts + j) * 128 + o] = fmax(acc[j], 0.0);
}

// ---------------- norm+split: xt64 -> normalized f32 -> hi/mid bf16 planes (linear layout)
__global__ __launch_bounds__(256) void norm_planes_kernel(
    const double* __restrict__ xt64, unsigned short* __restrict__ XH,
    unsigned short* __restrict__ XM)
{
    const int row = blockIdx.x * 4 + (threadIdx.x >> 6);
    const int lane = threadIdx.x & 63;
    double v0 = xt64[(size_t)row * 128 + lane * 2];
    double v1 = xt64[(size_t)row * 128 + lane * 2 + 1];
    double s = v0 * v0 + v1 * v1;
#pragma unroll
    for (int off = 32; off > 0; off >>= 1) s += __shfl_xor(s, off);
    double inv = 1.0 / fmax(sqrt(s), 1e-12);
    float x0 = (float)(v0 * inv), x1 = (float)(v1 * inv);
    unsigned short h0 = f2bf_rne(x0), h1 = f2bf_rne(x1);
    unsigned short m0 = f2bf_rne(x0 - bf2f(h0)), m1 = f2bf_rne(x1 - bf2f(h1));
    ushort2 hv; hv.x = h0; hv.y = h1;
    ushort2 mv; mv.x = m0; mv.y = m1;
    *(ushort2*)(XH + (size_t)row * 128 + lane * 2) = hv;
    *(ushort2*)(XM + (size_t)row * 128 + lane * 2) = mv;
}

// branchless sorted insert into 9 named (value,index) register slots, desc order,
// strict '>' so earlier (lower-index) arrivals win ties.
#define TOP9_INS(c, mg) do { \
    if ((c) > tv8) { \
        bool b0=(c)>tv0, b1=(c)>tv1, b2=(c)>tv2, b3=(c)>tv3; \
        bool b4=(c)>tv4, b5=(c)>tv5, b6=(c)>tv6, b7=(c)>tv7; \
        tv8 = b7?tv7:(c); ti8 = b7?ti7:(mg); \
        tv7 = b7?(b6?tv6:(c)):tv7; ti7 = b7?(b6?ti6:(mg)):ti7; \
        tv6 = b6?(b5?tv5:(c)):tv6; ti6 = b6?(b5?ti5:(mg)):ti6; \
        tv5 = b5?(b4?tv4:(c)):tv5; ti5 = b5?(b4?ti4:(mg)):ti5; \
        tv4 = b4?(b3?tv3:(c)):tv4; ti4 = b4?(b3?ti3:(mg)):ti4; \
        tv3 = b3?(b2?tv2:(c)):tv3; ti3 = b3?(b2?ti2:(mg)):ti3; \
        tv2 = b2?(b1?tv1:(c)):tv2; ti2 = b2?(b1?ti1:(mg)):ti2; \
        tv1 = b1?(b0?tv0:(c)):tv1; ti1 = b1?(b0?ti0:(mg)):ti1; \
        tv0 = b0?(c):tv0;          ti0 = b0?(mg):ti0; \
    } \
} while (0)

// ---------------- knn stage 1 v4: swapped-operand bf16x2-split MFMA gram.
// Each lane owns ONE row (col=lane&15 of C = our row); candidates = C rows.
// Per-lane top-9 in NAMED register scalars; 4-lane shuffle merge -> top-16/row.
__global__ __launch_bounds__(512, 2) void knn_mfma4_kernel(
    const unsigned short* __restrict__ XH, const unsigned short* __restrict__ XM,
    int* __restrict__ cand_out)
{
    __shared__ __align__(16) unsigned char smem[65536];  // 2 x 32KB (dbuf: 2 planes x 16KB)

    const int tid = threadIdx.x, wave = tid >> 6, lane = tid & 63;
    const int bid = blockIdx.x;
    const int b = (bid & 7) * 2 + ((bid >> 3) >> 4);
    const int n0 = ((bid >> 3) & 15) * 128;
    const unsigned short* Hb = XH + (size_t)b * 2048 * 128;
    const unsigned short* Mb = XM + (size_t)b * 2048 * 128;

    // our-row fragments (B-operand layout [k][j=lane&15]): row = n0+wave*16+(lane&15)
    s16x8 aH[4], aM[4];
    {
        int arow = n0 + wave * 16 + (lane & 15);
        const unsigned short* hrow = Hb + (size_t)arow * 128;
        const unsigned short* mrow = Mb + (size_t)arow * 128;
        int cb = (lane >> 4) * 8;
#pragma unroll
        for (int s = 0; s < 4; ++s) {
            aH[s] = *(const s16x8*)(hrow + s * 32 + cb);
            aM[s] = *(const s16x8*)(mrow + s * 32 + cb);
        }
    }

    // staging (gload_lds, linear dest / inverse-swizzled source) — unchanged from v3
    const unsigned short* Pb = (wave >> 2) ? Mb : Hb;
    const unsigned short* gsrc0; const unsigned short* gsrc1;
    const unsigned short* gsrc2; const unsigned short* gsrc3;
    {
        int r0 = (wave & 3) * 16 + 0 + (lane >> 4), c0 = (lane & 15) ^ (r0 & 7);
        int r1 = (wave & 3) * 16 + 4 + (lane >> 4), c1 = (lane & 15) ^ (r1 & 7);
        int r2 = (wave & 3) * 16 + 8 + (lane >> 4), c2 = (lane & 15) ^ (r2 & 7);
        int r3 = (wave & 3) * 16 + 12 + (lane >> 4), c3 = (lane & 15) ^ (r3 & 7);
        gsrc0 = Pb + (size_t)r0 * 128 + c0 * 8;
        gsrc1 = Pb + (size_t)r1 * 128 + c1 * 8;
        gsrc2 = Pb + (size_t)r2 * 128 + c2 * 8;
        gsrc3 = Pb + (size_t)r3 * 128 + c3 * 8;
    }
    const unsigned ldsbase = (wave * 4) * 1024;

    float tv0=-3.0e38f,tv1=-3.0e38f,tv2=-3.0e38f,tv3=-3.0e38f,tv4=-3.0e38f,
          tv5=-3.0e38f,tv6=-3.0e38f,tv7=-3.0e38f,tv8=-3.0e38f;
    int   ti0=0x3FFFFFFF,ti1=0x3FFFFFFF,ti2=0x3FFFFFFF,ti3=0x3FFFFFFF,ti4=0x3FFFFFFF,
          ti5=0x3FFFFFFF,ti6=0x3FFFFFFF,ti7=0x3FFFFFFF,ti8=0x3FFFFFFF;

    // prologue: stage tile 0 into buf 0
    gload_lds16(gsrc0, smem + ldsbase);
    gload_lds16(gsrc1, smem + ldsbase + 1024);
    gload_lds16(gsrc2, smem + ldsbase + 2048);
    gload_lds16(gsrc3, smem + ldsbase + 3072);
    __syncthreads();

    int cur = 0;
    for (int t = 0; t < 32; ++t) {
        const int m0t = t * 64;
        if (t < 31) {  // stage tile t+1 into buf cur^1 (overlaps compute)
            size_t go = (size_t)(m0t + 64) * 128;
            unsigned lb = (cur ^ 1) * 32768 + ldsbase;
            gload_lds16(gsrc0 + go, smem + lb);
            gload_lds16(gsrc1 + go, smem + lb + 1024);
            gload_lds16(gsrc2 + go, smem + lb + 2048);
            gload_lds16(gsrc3 + go, smem + lb + 3072);
        }
        const unsigned char* B0 = smem + cur * 32768;
        const unsigned char* B1 = B0 + 16384;
#pragma unroll
        for (int ct = 0; ct < 4; ++ct) {
            f32x4 acc; acc[0] = 0.f; acc[1] = 0.f; acc[2] = 0.f; acc[3] = 0.f;
            int r = ct * 16 + (lane & 15);
#pragma unroll
            for (int s = 0; s < 4; ++s) {
                int off = r * 256 + (((s * 64) + ((lane >> 4) * 16)) ^ ((r & 7) << 4));
                s16x8 bH = *(const s16x8*)(B0 + off);
                s16x8 bM = *(const s16x8*)(B1 + off);
                // swapped operands: tile rows are the A-operand (C rows = candidates),
                // our rows are the B-operand (C cols = lane&15)
                acc = __builtin_amdgcn_mfma_f32_16x16x32_bf16(bH, aH[s], acc, 0, 0, 0);
                acc = __builtin_amdgcn_mfma_f32_16x16x32_bf16(bM, aH[s], acc, 0, 0, 0);
                acc = __builtin_amdgcn_mfma_f32_16x16x32_bf16(bH, aM[s], acc, 0, 0, 0);
                acc = __builtin_amdgcn_mfma_f32_16x16x32_bf16(bM, aM[s], acc, 0, 0, 0);
            }
            // candidates m = m0t + ct*16 + (lane>>4)*4 + reg, ascending in (ct,reg)
            int mbase = m0t + ct * 16 + (lane >> 4) * 4;
            float c0 = acc[0], c1 = acc[1], c2 = acc[2], c3 = acc[3];
            float gmx = fmaxf(fmaxf(c0, c1), fmaxf(c2, c3));
            if (gmx > tv8) {
                TOP9_INS(c0, mbase + 0);
                TOP9_INS(c1, mbase + 1);
                TOP9_INS(c2, mbase + 2);
                TOP9_INS(c3, mbase + 3);
            }
        }
        __syncthreads();
        cur ^= 1;
    }

    // merge: 4 lanes (g=lane>>4) per row hold disjoint sorted top-9 lists.
    // 16 passes of butterfly max over strides 16,32 with (val desc, idx asc).
    const int g = lane >> 4;
    const int row = b * 2048 + n0 + wave * 16 + (lane & 15);
#pragma unroll
    for (int pass = 0; pass < 16; ++pass) {
        float hv = tv0; int hi = ti0;
        float rv = hv; int ri = hi;
        float ov = __shfl_xor(rv, 16); int oi = __shfl_xor(ri, 16);
        bool tk = (ov > rv) || (ov == rv && oi < ri);
        rv = tk ? ov : rv; ri = tk ? oi : ri;
        ov = __shfl_xor(rv, 32); oi = __shfl_xor(ri, 32);
        tk = (ov > rv) || (ov == rv && oi < ri);
        rv = tk ? ov : rv; ri = tk ? oi : ri;
        (void)hv;
        if (hi == ri) {  // this lane's head won -> pop (indices unique per row)
            tv0=tv1; ti0=ti1; tv1=tv2; ti1=ti2; tv2=tv3; ti2=ti3; tv3=tv4; ti3=ti4;
            tv4=tv5; ti4=ti5; tv5=tv6; ti5=ti6; tv6=tv7; ti6=ti7; tv7=tv8; ti7=ti8;
            tv8 = -3.4e38f; ti8 = 0x7FFFFFFF;
        }
        if (g == (pass & 3)) cand_out[(size_t)row * 16 + pass] = ri;
    }
}

// ---------------- knn stage 2 (f64): exact rescore of 16 candidates, pick top-9 (stable ties)
__global__ __launch_bounds__(256) void rescore_kernel(
    const double* __restrict__ xt64, const int* __restrict__ cand, int* __restrict__ idx_out)
{
    const int wid = threadIdx.x >> 6, lane = threadIdx.x & 63;
    const int n = blockIdx.x * 4 + wid;
    const int b = n >> 11;
    const double* Xb = xt64 + (size_t)b * 2048 * 128;
    const double* xr = xt64 + (size_t)n * 128;
    double a0 = xr[lane * 2], a1 = xr[lane * 2 + 1];
    double snn = a0 * a0 + a1 * a1;
#pragma unroll
    for (int off = 32; off > 0; off >>= 1) snn += __shfl_xor(snn, off);
    double invn = 1.0 / fmax(sqrt(snn), 1e-12);
    double sc[16]; int cd[16];
#pragma unroll
    for (int k = 0; k < 16; ++k) {
        int m = cand[(size_t)n * 16 + k];
        const double* xm = Xb + (size_t)m * 128;
        double m0v = xm[lane * 2], m1v = xm[lane * 2 + 1];
        double dnm = a0 * m0v + a1 * m1v;
        double dmm = m0v * m0v + m1v * m1v;
#pragma unroll
        for (int off = 32; off > 0; off >>= 1) {
            dnm += __shfl_xor(dnm, off);
            dmm += __shfl_xor(dmm, off);
        }
        double invm = 1.0 / fmax(sqrt(dmm), 1e-12);
        sc[k] = 2.0 * dnm * invn * invm - dmm * invm * invm;
        cd[k] = m;
    }
    if (lane == 0) {
        unsigned usedmask = 0;
        size_t ob = (size_t)n * 9;
        for (int p = 0; p < 9; ++p) {
            double best = -1.0e300; int bi = 1 << 30; int bp = 0;
#pragma unroll
            for (int j = 0; j < 16; ++j) {
                if (usedmask & (1u << j)) continue;
                if (sc[j] > best || (sc[j] == best && cd[j] < bi)) { best = sc[j]; bi = cd[j]; bp = j; }
            }
            usedmask |= 1u << bp;
            idx_out[ob + p] = bi;
        }
    }
}

// ---------------- f64 GEMM (K=128, staged in 2 chunks of 64 -> 67.6 KB LDS, 2 blocks/CU).
// mode 0: G=Xt@[W1;W2]^T (ld 256); 1: gelu affine; 2: affine (+f32 copy)
__global__ __launch_bounds__(256) void gemm64_kernel(
    const double* __restrict__ A, const float* __restrict__ W,
    const float* __restrict__ bias, const float* __restrict__ gamma,
    const float* __restrict__ beta, double* __restrict__ out,
    float* __restrict__ out32, int mode)
{
    __shared__ double As[64][66];
    __shared__ double Ws[64][66];
    const int m0 = blockIdx.x * 64;
    const int j0 = blockIdx.y * 64;
    const int ri = threadIdx.x >> 4, ci = threadIdx.x & 15;
    double acc[4][4];
#pragma unroll
    for (int u = 0; u < 4; ++u)
#pragma unroll
        for (int v = 0; v < 4; ++v) acc[u][v] = 0.0;

    for (int k0 = 0; k0 < 128; k0 += 64) {
        __syncthreads();
        for (int e = threadIdx.x; e < 64 * 64; e += 256) {
            int r = e >> 6, c = e & 63;
            As[r][c] = A[(size_t)(m0 + r) * 128 + k0 + c];
            int j = j0 + r;
            double wv;
            if (mode == 0) wv = (j < 128) ? (double)W[j * 256 + k0 + c] : (double)W[(j - 128) * 256 + 128 + k0 + c];
            else           wv = (double)W[j * 128 + k0 + c];
            Ws[r][c] = wv;
        }
        __syncthreads();
        for (int c = 0; c < 64; c += 2) {
            double a0[4], a1[4], w0[4], w1[4];
#pragma unroll
            for (int u = 0; u < 4; ++u) { a0[u] = As[ri + 16 * u][c]; a1[u] = As[ri + 16 * u][c + 1]; }
#pragma unroll
            for (int v = 0; v < 4; ++v) { w0[v] = Ws[ci + 16 * v][c]; w1[v] = Ws[ci + 16 * v][c + 1]; }
#pragma unroll
            for (int u = 0; u < 4; ++u)
#pragma unroll
                for (int v = 0; v < 4; ++v)
                    acc[u][v] = fma(a1[u], w1[v], fma(a0[u], w0[v], acc[u][v]));
        }
    }
#pragma unroll
    for (int u = 0; u < 4; ++u) {
        int row = m0 + ri + 16 * u;
#pragma unroll
        for (int v = 0; v < 4; ++v) {
            int jl = ci + 16 * v;
            double val = acc[u][v];
            if (mode == 0) {
                out[(size_t)row * 256 + j0 + jl] = val;
            } else {
                int jg = j0 + jl;
                double z = (val + (double)bias[jg]) * (double)gamma[jg] + (double)beta[jg];
                if (mode == 1) {
                    out[(size_t)row * 128 + jg] = gelu64(z);
                } else {
                    out[(size_t)row * 128 + jg] = z;
                    out32[(size_t)row * 128 + jg] = (float)z;
                }
            }
        }
    }
}

// ---------------- combine64 (in-place residual): xt += max_k gelu((G1+b-G2_i+G2_j)*gamma+beta)
__global__ __launch_bounds__(256) void combine64_kernel(
    double* __restrict__ xt, const double* __restrict__ G,
    const int* __restrict__ idx, const float* __restrict__ bias,
    const float* __restrict__ gamma, const float* __restrict__ beta)
{
    const int row = blockIdx.x * 2 + (threadIdx.x >> 7);
    const int o = threadIdx.x & 127;
    const int b = row >> 11;
    const double* Gb = G + (size_t)(b * 2048) * 256;
    const int* id9 = idx + (size_t)row * 9;
    double g1  = G[(size_t)row * 256 + o];
    double g2i = G[(size_t)row * 256 + 128 + o];
    double base = g1 + (double)bias[o] - g2i;
    double gm = (double)gamma[o], bt = (double)beta[o];
    double mx = -1.0e300;
#pragma unroll
    for (int k = 0; k < 9; ++k) {
        int j = id9[k];
        double h = base + Gb[(size_t)j * 256 + 128 + o];
        double z = h * gm + bt;
        mx = fmax(mx, gelu64(z));
    }
    xt[(size_t)row * 128 + o] += mx;
}

// ---------------- f32 GEMM (block-2 value path). modes as gemm64
__global__ __launch_bounds__(256) void gemm128_kernel(
    const float* __restrict__ A, const float* __restrict__ W,
    const float* __restrict__ bias, const float* __restrict__ gamma,
    const float* __restrict__ beta, float* __restrict__ out, int mode)
{
    __shared__ float Al[128][132];
    __shared__ float Wl[128][132];
    const int m0 = blockIdx.x * 128;
    const int j0 = blockIdx.y * 128;
    for (int e = threadIdx.x; e < 128 * 32; e += 256) {
        int r = e >> 5, q = e & 31;
        *(float4*)&Al[r][q * 4] = *(const float4*)(A + (size_t)(m0 + r) * 128 + q * 4);
    }
    for (int e = threadIdx.x; e < 128 * 32; e += 256) {
        int jj = e >> 5, q = e & 31;
        int c = q * 4;
        const float* src;
        if (mode == 0) {
            int j = j0 + jj;
            src = (j < 128) ? (W + j * 256 + c) : (W + (j - 128) * 256 + 128 + c);
        } else {
            src = W + jj * 128 + c;
        }
        *(float4*)&Wl[jj][c] = *(const float4*)src;
    }
    __syncthreads();
    const int ri = threadIdx.x >> 4, ci = threadIdx.x & 15;
    float acc[8][8];
#pragma unroll
    for (int u = 0; u < 8; ++u)
#pragma unroll
        for (int v = 0; v < 8; ++v) acc[u][v] = 0.0f;
    for (int c = 0; c < 128; c += 4) {
        float4 a4[8];
#pragma unroll
        for (int u = 0; u < 8; ++u) a4[u] = *(const float4*)&Al[ri + 16 * u][c];
#pragma unroll
        for (int v = 0; v < 8; ++v) {
            float4 w4 = *(const float4*)&Wl[ci + 16 * v][c];
#pragma unroll
            for (int u = 0; u < 8; ++u) {
                acc[u][v] = fmaf(a4[u].x, w4.x, fmaf(a4[u].y, w4.y,
                            fmaf(a4[u].z, w4.z, fmaf(a4[u].w, w4.w, acc[u][v]))));
            }
        }
    }
#pragma unroll
    for (int u = 0; u < 8; ++u) {
        int row = m0 + ri + 16 * u;
#pragma unroll
        for (int v = 0; v < 8; ++v) {
            int j = ci + 16 * v;
            float val = acc[u][v];
            if (mode == 0) {
                out[(size_t)row * 256 + j0 + j] = val;
            } else if (mode == 1) {
                float z = (val + bias[j]) * gamma[j] + beta[j];
                out[(size_t)row * 128 + j] = gelu_exact(z);
            } else {
                float z = (val + bias[j]) * gamma[j] + beta[j];
                out[(size_t)row * 128 + j] = z;
            }
        }
    }
}

// ---------------- combine f32 (block 2; in-place safe: reads only own row of xt)
__global__ __launch_bounds__(256) void combine_kernel(
    const float* __restrict__ xt, const float* __restrict__ G,
    const int* __restrict__ idx, const float* __restrict__ bias,
    const float* __restrict__ gamma, const float* __restrict__ beta,
    float* __restrict__ xt2)
{
    const int row = blockIdx.x * 2 + (threadIdx.x >> 7);
    const int o = threadIdx.x & 127;
    const int b = row >> 11;
    const float* Gb = G + (size_t)(b * 2048) * 256;
    const int* id9 = idx + (size_t)row * 9;
    float g1  = G[(size_t)row * 256 + o];
    float g2i = G[(size_t)row * 256 + 128 + o];
    float base = g1 + bias[o] - g2i;
    float gm = gamma[o], bt = beta[o];
    float mx = -3.4e38f;
#pragma unroll
    for (int k = 0; k < 9; ++k) {
        int j = id9[k];
        float h = base + Gb[(size_t)j * 256 + 128 + o];
        float z = h * gm + bt;
        mx = fmaxf(mx, gelu_exact(z));
    }
    xt2[(size_t)row * 128 + o] = xt[(size_t)row * 128 + o] + mx;
}

extern "C" void kernel_launch(void* const* d_in, const int* in_sizes, int n_in,
                              void* d_out, int out_size, void* d_ws, size_t ws_size,
                              hipStream_t stream)
{
    const float* ts       = (const float*)d_in[0];
    const float* conv1_w  = (const float*)d_in[1];
    const float* conv1_b  = (const float*)d_in[2];
    const float* conv2_w  = (const float*)d_in[3];
    const float* conv2_b  = (const float*)d_in[4];
    const float* gconv_w  = (const float*)d_in[5];
    const float* gconv_b  = (const float*)d_in[6];
    const float* gconv_g  = (const float*)d_in[7];
    const float* gconv_be = (const float*)d_in[8];
    const float* ffn1_w   = (const float*)d_in[9];
    const float* ffn1_b   = (const float*)d_in[10];
    const float* ffn1_g   = (const float*)d_in[11];
    const float* ffn1_be  = (const float*)d_in[12];
    const float* ffn2_w   = (const float*)d_in[13];
    const float* ffn2_b   = (const float*)d_in[14];
    const float* ffn2_g   = (const float*)d_in[15];
    const float* ffn2_be  = (const float*)d_in[16];
    (void)in_sizes; (void)n_in; (void)out_size; (void)ws_size;

    // ---- workspace layout (byte offsets), lifetime-overlaid; peak ~102 MB ----
    char* base = (char*)d_ws;
    double*         XT64  = (double*)(base + 0);            // 33.55 MB
    double*         H1_64 = (double*)(base + 33554432);     // 16.78 MB (conv phase only)
    unsigned short* XH    = (unsigned short*)(base + 33554432); // 8.39 MB (norm -> knn)
    unsigned short* XM    = (unsigned short*)(base + 41943040); // 8.39 MB (norm -> knn)
    int*            CAND  = (int*)   (base + 50331648);     // 2.10 MB  (knn -> rescore)
    double*         G64   = (double*)(base + 33554432);     // 67.11 MB (gemm0 -> combine, blk1)
    double*         H64   = (double*)(base + 33554432);     // 33.55 MB (ffn1 -> ffn2, blk1)
    float*          XT32P = (float*) (base + 67108864);     // 16.78 MB (blk1 ffn2 -> blk2 value path)
    int*            IDX   = (int*)   (base + 100663296);    // 1.18 MB  (rescore -> combine)
    float*          G32   = (float*) (base + 33554432);     // 33.55 MB (blk2)
    float*          H32   = (float*) (base + 33554432);     // 16.78 MB (blk2 ffn)

    float* fout = (float*)d_out;

    conv1_kernel64<<<dim3(64, 16), 256, 0, stream>>>(ts, conv1_w, conv1_b, H1_64);
    conv2_kernel64<<<dim3(64, 16), 256, 0, stream>>>(H1_64, conv2_w, conv2_b, XT64);

    // ---------- block 1 (f64 value path; indices exact) ----------
    norm_planes_kernel<<<8192, 256, 0, stream>>>(XT64, XH, XM);
    knn_mfma4_kernel<<<256, 512, 0, stream>>>(XH, XM, CAND);
    rescore_kernel<<<8192, 256, 0, stream>>>(XT64, CAND, IDX);
    gemm64_kernel<<<dim3(512, 4), 256, 0, stream>>>(
        XT64, gconv_w, nullptr, nullptr, nullptr, G64, nullptr, 0);
    combine64_kernel<<<16384, 256, 0, stream>>>(
        XT64, G64, IDX, gconv_b, gconv_g, gconv_be);
    gemm64_kernel<<<dim3(512, 2), 256, 0, stream>>>(
        XT64, ffn1_w, ffn1_b, ffn1_g, ffn1_be, H64, nullptr, 1);
    gemm64_kernel<<<dim3(512, 2), 256, 0, stream>>>(
        H64, ffn2_w, ffn2_b, ffn2_g, ffn2_be, XT64, XT32P, 2);

    // ---------- block 2 (indices exact via f64; value path f32) ----------
    norm_planes_kernel<<<8192, 256, 0, stream>>>(XT64, XH, XM);
    knn_mfma4_kernel<<<256, 512, 0, stream>>>(XH, XM, CAND);
    rescore_kernel<<<8192, 256, 0, stream>>>(XT64, CAND, IDX);
    gemm128_kernel<<<dim3(256, 2), 256, 0, stream>>>(
        XT32P, gconv_w + 32768, nullptr, nullptr, nullptr, G32, 0);
    combine_kernel<<<16384, 256, 0, stream>>>(
        XT32P, G32, IDX, gconv_b + 128, gconv_g + 128, gconv_be + 128, XT32P);
    gemm128_kernel<<<dim3(256, 1), 256, 0, stream>>>(
        XT32P, ffn1_w + 16384, ffn1_b + 128, ffn1_g + 128, ffn1_be + 128, H32, 1);
    gemm128_kernel<<<dim3(256, 1), 256, 0, stream>>>(
        H32, ffn2_w + 16384, ffn2_b + 128, ffn2_g + 128, ffn2_be + 128, fout, 2);
}

// Round 8
// 1082.946 us; speedup vs baseline: 2.6706x; 1.1723x over previous
//
#include <hip/hip_runtime.h>
#include <hip/hip_bf16.h>

#define DEV_INLINE __device__ __forceinline__

typedef short s16x8 __attribute__((ext_vector_type(8)));
typedef float f32x4 __attribute__((ext_vector_type(4)));

DEV_INLINE float gelu_exact(float x) {
    return 0.5f * x * (1.0f + erff(x * 0.70710678118654752440f));
}
DEV_INLINE double gelu64(double x) {
    return 0.5 * x * (1.0 + erf(x * 0.70710678118654752440));
}
DEV_INLINE unsigned short f2bf_rne(float f) {
    unsigned u = __float_as_uint(f);
    unsigned r = u + 0x7FFFu + ((u >> 16) & 1u);
    return (unsigned short)(r >> 16);
}
DEV_INLINE float bf2f(unsigned short h) { return __uint_as_float(((unsigned)h) << 16); }

DEV_INLINE void gload_lds16(const void* g, void* l) {
    __builtin_amdgcn_global_load_lds(
        (const __attribute__((address_space(1))) unsigned int*)g,
        (__attribute__((address_space(3))) unsigned int*)l, 16, 0, 0);
}

// ---------------- conv1 (f64): ts (16,100,2048) f32 -> relu(causal conv d=1) -> h1 (16,64,2048) f64
__global__ __launch_bounds__(256) void conv1_kernel64(
    const float* __restrict__ x, const float* __restrict__ w,
    const float* __restrict__ bias, double* __restrict__ y)
{
    const int b = blockIdx.y;
    const int t0 = blockIdx.x * 32;
    __shared__ double xs[100][34];
    for (int e = threadIdx.x; e < 100 * 34; e += 256) {
        int i = e / 34, u = e - i * 34;
        int t = t0 - 2 + u;
        xs[i][u] = (t >= 0) ? (double)x[(b * 100 + i) * 2048 + t] : 0.0;
    }
    __syncthreads();
    const int o = threadIdx.x & 63;
    const int ts = (threadIdx.x >> 6) * 8;
    double acc[8];
    double bv = (double)bias[o];
#pragma unroll
    for (int j = 0; j < 8; ++j) acc[j] = bv;
    const float* wo = w + o * 300;
    for (int i = 0; i < 100; ++i) {
        double w0 = (double)wo[i * 3 + 0], w1 = (double)wo[i * 3 + 1], w2 = (double)wo[i * 3 + 2];
#pragma unroll
        for (int j = 0; j < 8; ++j) {
            acc[j] = fma(w0, xs[i][ts + j],
                     fma(w1, xs[i][ts + j + 1],
                     fma(w2, xs[i][ts + j + 2], acc[j])));
        }
    }
#pragma unroll
    for (int j = 0; j < 8; ++j)
        y[(b * 64 + o) * 2048 + t0 + ts + j] = fmax(acc[j], 0.0);
}

// ---------------- conv2 (f64): h1 -> relu(causal conv d=2) -> xt64 (16,2048,128) transposed
__global__ __launch_bounds__(256) void conv2_kernel64(
    const double* __restrict__ x, const float* __restrict__ w,
    const float* __restrict__ bias, double* __restrict__ xt)
{
    const int b = blockIdx.y;
    const int t0 = blockIdx.x * 32;
    __shared__ double xs[64][36];
    for (int e = threadIdx.x; e < 64 * 36; e += 256) {
        int i = e / 36, u = e - i * 36;
        int t = t0 - 4 + u;
        xs[i][u] = (t >= 0) ? x[(b * 64 + i) * 2048 + t] : 0.0;
    }
    __syncthreads();
    const int o = threadIdx.x & 127;
    const int ts = (threadIdx.x >> 7) * 16;
    double acc[16];
    double bv = (double)bias[o];
#pragma unroll
    for (int j = 0; j < 16; ++j) acc[j] = bv;
    const float* wo = w + o * 192;
    for (int i = 0; i < 64; ++i) {
        double w0 = (double)wo[i * 3 + 0], w1 = (double)wo[i * 3 + 1], w2 = (double)wo[i * 3 + 2];
#pragma unroll
        for (int j = 0; j < 16; ++j) {
            acc[j] = fma(w0, xs[i][ts + j],
                     fma(w1, xs[i][ts + j + 2],
                     fma(w2, xs[i][ts + j + 4], acc[j])));
        }
    }
#pragma unroll
    for (int j = 0; j < 16; ++j)
        xt[(size_t)(b * 2048 + t0 + ts + j) * 128 + o] = fmax(acc[j], 0.0);
}

// ---------------- norm+split: xt64 -> f64-normalized rows (XN64, SQ64) + hi/mid bf16 planes
// NOTE: XN64 may alias xt64 (in-place): each element is read only by the thread that writes it,
// and the row-norm is reduced in registers before any write.
__global__ __launch_bounds__(256) void norm_planes_kernel(
    const double* __restrict__ xt64, unsigned short* __restrict__ XH,
    unsigned short* __restrict__ XM, double* __restrict__ XN64,
    double* __restrict__ SQ64)
{
    const int row = blockIdx.x * 4 + (threadIdx.x >> 6);
    const int lane = threadIdx.x & 63;
    double v0 = xt64[(size_t)row * 128 + lane * 2];
    double v1 = xt64[(size_t)row * 128 + lane * 2 + 1];
    double s = v0 * v0 + v1 * v1;
#pragma unroll
    for (int off = 32; off > 0; off >>= 1) s += __shfl_xor(s, off);
    double inv = 1.0 / fmax(sqrt(s), 1e-12);
    double n0 = v0 * inv, n1 = v1 * inv;
    XN64[(size_t)row * 128 + lane * 2]     = n0;
    XN64[(size_t)row * 128 + lane * 2 + 1] = n1;
    double q = n0 * n0 + n1 * n1;
#pragma unroll
    for (int off = 32; off > 0; off >>= 1) q += __shfl_xor(q, off);
    if (lane == 0) SQ64[row] = q;
    float x0 = (float)n0, x1 = (float)n1;
    unsigned short h0 = f2bf_rne(x0), h1 = f2bf_rne(x1);
    unsigned short m0 = f2bf_rne(x0 - bf2f(h0)), m1 = f2bf_rne(x1 - bf2f(h1));
    ushort2 hv; hv.x = h0; hv.y = h1;
    ushort2 mv; mv.x = m0; mv.y = m1;
    *(ushort2*)(XH + (size_t)row * 128 + lane * 2) = hv;
    *(ushort2*)(XM + (size_t)row * 128 + lane * 2) = mv;
}

// branchless sorted insert into 9 named (value,index) register slots, desc order,
// strict '>' so earlier (lower-index) arrivals win ties.
#define TOP9_INS(c, mg) do { \
    if ((c) > tv8) { \
        bool b0=(c)>tv0, b1=(c)>tv1, b2=(c)>tv2, b3=(c)>tv3; \
        bool b4=(c)>tv4, b5=(c)>tv5, b6=(c)>tv6, b7=(c)>tv7; \
        tv8 = b7?tv7:(c); ti8 = b7?ti7:(mg); \
        tv7 = b7?(b6?tv6:(c)):tv7; ti7 = b7?(b6?ti6:(mg)):ti7; \
        tv6 = b6?(b5?tv5:(c)):tv6; ti6 = b6?(b5?ti5:(mg)):ti6; \
        tv5 = b5?(b4?tv4:(c)):tv5; ti5 = b5?(b4?ti4:(mg)):ti5; \
        tv4 = b4?(b3?tv3:(c)):tv4; ti4 = b4?(b3?ti3:(mg)):ti4; \
        tv3 = b3?(b2?tv2:(c)):tv3; ti3 = b3?(b2?ti2:(mg)):ti3; \
        tv2 = b2?(b1?tv1:(c)):tv2; ti2 = b2?(b1?ti1:(mg)):ti2; \
        tv1 = b1?(b0?tv0:(c)):tv1; ti1 = b1?(b0?ti0:(mg)):ti1; \
        tv0 = b0?(c):tv0;          ti0 = b0?(mg):ti0; \
    } \
} while (0)

// ---------------- knn stage 1 v4: swapped-operand bf16x2-split MFMA gram.
// Each lane owns ONE row (col=lane&15 of C = our row); candidates = C rows.
// Per-lane top-9 in NAMED register scalars; 4-lane shuffle merge -> top-16/row.
__global__ __launch_bounds__(512, 2) void knn_mfma4_kernel(
    const unsigned short* __restrict__ XH, const unsigned short* __restrict__ XM,
    int* __restrict__ cand_out)
{
    __shared__ __align__(16) unsigned char smem[65536];  // 2 x 32KB (dbuf: 2 planes x 16KB)

    const int tid = threadIdx.x, wave = tid >> 6, lane = tid & 63;
    const int bid = blockIdx.x;
    const int b = (bid & 7) * 2 + ((bid >> 3) >> 4);
    const int n0 = ((bid >> 3) & 15) * 128;
    const unsigned short* Hb = XH + (size_t)b * 2048 * 128;
    const unsigned short* Mb = XM + (size_t)b * 2048 * 128;

    // our-row fragments (B-operand layout [k][j=lane&15]): row = n0+wave*16+(lane&15)
    s16x8 aH[4], aM[4];
    {
        int arow = n0 + wave * 16 + (lane & 15);
        const unsigned short* hrow = Hb + (size_t)arow * 128;
        const unsigned short* mrow = Mb + (size_t)arow * 128;
        int cb = (lane >> 4) * 8;
#pragma unroll
        for (int s = 0; s < 4; ++s) {
            aH[s] = *(const s16x8*)(hrow + s * 32 + cb);
            aM[s] = *(const s16x8*)(mrow + s * 32 + cb);
        }
    }

    // staging (gload_lds, linear dest / inverse-swizzled source)
    const unsigned short* Pb = (wave >> 2) ? Mb : Hb;
    const unsigned short* gsrc0; const unsigned short* gsrc1;
    const unsigned short* gsrc2; const unsigned short* gsrc3;
    {
        int r0 = (wave & 3) * 16 + 0 + (lane >> 4), c0 = (lane & 15) ^ (r0 & 7);
        int r1 = (wave & 3) * 16 + 4 + (lane >> 4), c1 = (lane & 15) ^ (r1 & 7);
        int r2 = (wave & 3) * 16 + 8 + (lane >> 4), c2 = (lane & 15) ^ (r2 & 7);
        int r3 = (wave & 3) * 16 + 12 + (lane >> 4), c3 = (lane & 15) ^ (r3 & 7);
        gsrc0 = Pb + (size_t)r0 * 128 + c0 * 8;
        gsrc1 = Pb + (size_t)r1 * 128 + c1 * 8;
        gsrc2 = Pb + (size_t)r2 * 128 + c2 * 8;
        gsrc3 = Pb + (size_t)r3 * 128 + c3 * 8;
    }
    const unsigned ldsbase = (wave * 4) * 1024;

    float tv0=-3.0e38f,tv1=-3.0e38f,tv2=-3.0e38f,tv3=-3.0e38f,tv4=-3.0e38f,
          tv5=-3.0e38f,tv6=-3.0e38f,tv7=-3.0e38f,tv8=-3.0e38f;
    int   ti0=0x3FFFFFFF,ti1=0x3FFFFFFF,ti2=0x3FFFFFFF,ti3=0x3FFFFFFF,ti4=0x3FFFFFFF,
          ti5=0x3FFFFFFF,ti6=0x3FFFFFFF,ti7=0x3FFFFFFF,ti8=0x3FFFFFFF;

    // prologue: stage tile 0 into buf 0
    gload_lds16(gsrc0, smem + ldsbase);
    gload_lds16(gsrc1, smem + ldsbase + 1024);
    gload_lds16(gsrc2, smem + ldsbase + 2048);
    gload_lds16(gsrc3, smem + ldsbase + 3072);
    __syncthreads();

    int cur = 0;
    for (int t = 0; t < 32; ++t) {
        const int m0t = t * 64;
        if (t < 31) {  // stage tile t+1 into buf cur^1 (overlaps compute)
            size_t go = (size_t)(m0t + 64) * 128;
            unsigned lb = (cur ^ 1) * 32768 + ldsbase;
            gload_lds16(gsrc0 + go, smem + lb);
            gload_lds16(gsrc1 + go, smem + lb + 1024);
            gload_lds16(gsrc2 + go, smem + lb + 2048);
            gload_lds16(gsrc3 + go, smem + lb + 3072);
        }
        const unsigned char* B0 = smem + cur * 32768;
        const unsigned char* B1 = B0 + 16384;
#pragma unroll
        for (int ct = 0; ct < 4; ++ct) {
            f32x4 acc; acc[0] = 0.f; acc[1] = 0.f; acc[2] = 0.f; acc[3] = 0.f;
            int r = ct * 16 + (lane & 15);
#pragma unroll
            for (int s = 0; s < 4; ++s) {
                int off = r * 256 + (((s * 64) + ((lane >> 4) * 16)) ^ ((r & 7) << 4));
                s16x8 bH = *(const s16x8*)(B0 + off);
                s16x8 bM = *(const s16x8*)(B1 + off);
                acc = __builtin_amdgcn_mfma_f32_16x16x32_bf16(bH, aH[s], acc, 0, 0, 0);
                acc = __builtin_amdgcn_mfma_f32_16x16x32_bf16(bM, aH[s], acc, 0, 0, 0);
                acc = __builtin_amdgcn_mfma_f32_16x16x32_bf16(bH, aM[s], acc, 0, 0, 0);
                acc = __builtin_amdgcn_mfma_f32_16x16x32_bf16(bM, aM[s], acc, 0, 0, 0);
            }
            int mbase = m0t + ct * 16 + (lane >> 4) * 4;
            float c0 = acc[0], c1 = acc[1], c2 = acc[2], c3 = acc[3];
            float gmx = fmaxf(fmaxf(c0, c1), fmaxf(c2, c3));
            if (gmx > tv8) {
                TOP9_INS(c0, mbase + 0);
                TOP9_INS(c1, mbase + 1);
                TOP9_INS(c2, mbase + 2);
                TOP9_INS(c3, mbase + 3);
            }
        }
        __syncthreads();
        cur ^= 1;
    }

    // merge: 4 lanes (g=lane>>4) per row hold disjoint sorted top-9 lists.
    const int g = lane >> 4;
    const int row = b * 2048 + n0 + wave * 16 + (lane & 15);
#pragma unroll
    for (int pass = 0; pass < 16; ++pass) {
        float hv = tv0; int hi = ti0;
        float rv = hv; int ri = hi;
        float ov = __shfl_xor(rv, 16); int oi = __shfl_xor(ri, 16);
        bool tk = (ov > rv) || (ov == rv && oi < ri);
        rv = tk ? ov : rv; ri = tk ? oi : ri;
        ov = __shfl_xor(rv, 32); oi = __shfl_xor(ri, 32);
        tk = (ov > rv) || (ov == rv && oi < ri);
        rv = tk ? ov : rv; ri = tk ? oi : ri;
        (void)hv;
        if (hi == ri) {
            tv0=tv1; ti0=ti1; tv1=tv2; ti1=ti2; tv2=tv3; ti2=ti3; tv3=tv4; ti3=ti4;
            tv4=tv5; ti4=ti5; tv5=tv6; ti5=ti6; tv6=tv7; ti6=ti7; tv7=tv8; ti7=ti8;
            tv8 = -3.4e38f; ti8 = 0x7FFFFFFF;
        }
        if (g == (pass & 3)) cand_out[(size_t)row * 16 + pass] = ri;
    }
}

// ---------------- knn stage 2 v2 (f64): parallel rescore of 16 candidates from
// precomputed normalized rows; score = 2*dot(xn_n,xn_m) - SQ64[m].
// lane = (candidate k = lane&15, chunk g = lane>>4 of 32 elems); 2-step reduce;
// 9 pop-max passes over the 16-lane group (val desc, idx asc — stable ties).
__global__ __launch_bounds__(256) void rescore2_kernel(
    const double* __restrict__ XN64, const double* __restrict__ SQ64,
    const int* __restrict__ cand, int* __restrict__ idx_out)
{
    const int wid = threadIdx.x >> 6, lane = threadIdx.x & 63;
    const int n = blockIdx.x * 4 + wid;
    const int b = n >> 11;
    const int k = lane & 15, g = lane >> 4;
    const int m = cand[(size_t)n * 16 + k];
    const double* xm = XN64 + ((size_t)(b * 2048) + m) * 128 + g * 32;
    const double* xq = XN64 + (size_t)n * 128 + g * 32;
    double d0 = 0.0, d1 = 0.0, d2 = 0.0, d3 = 0.0;
#pragma unroll
    for (int j = 0; j < 32; j += 4) {
        d0 = fma(xq[j + 0], xm[j + 0], d0);
        d1 = fma(xq[j + 1], xm[j + 1], d1);
        d2 = fma(xq[j + 2], xm[j + 2], d2);
        d3 = fma(xq[j + 3], xm[j + 3], d3);
    }
    double d = (d0 + d1) + (d2 + d3);
    d += __shfl_xor(d, 16);
    d += __shfl_xor(d, 32);
    double sc = 2.0 * d - SQ64[(size_t)b * 2048 + m];
    int mi = m;
    size_t ob = (size_t)n * 9;
#pragma unroll
    for (int p = 0; p < 9; ++p) {
        double rv = sc; int ri = mi;
#pragma unroll
        for (int s = 1; s < 16; s <<= 1) {
            double ov = __shfl_xor(rv, s);
            int oi = __shfl_xor(ri, s);
            bool tk = (ov > rv) || (ov == rv && oi < ri);
            rv = tk ? ov : rv; ri = tk ? oi : ri;
        }
        if (mi == ri) sc = -1.0e300;   // pop (candidate indices unique per row)
        if (lane == p) idx_out[ob + p] = ri;
    }
}

// ---------------- f64 GEMM (K=128, staged in 2 chunks of 64 -> 67.6 KB LDS, 2 blocks/CU).
// mode 0: G=Xt@[W1;W2]^T (ld 256); 1: gelu affine; 2: affine (+f32 copy)
__global__ __launch_bounds__(256) void gemm64_kernel(
    const double* __restrict__ A, const float* __restrict__ W,
    const float* __restrict__ bias, const float* __restrict__ gamma,
    const float* __restrict__ beta, double* __restrict__ out,
    float* __restrict__ out32, int mode)
{
    __shared__ double As[64][66];
    __shared__ double Ws[64][66];
    const int m0 = blockIdx.x * 64;
    const int j0 = blockIdx.y * 64;
    const int ri = threadIdx.x >> 4, ci = threadIdx.x & 15;
    double acc[4][4];
#pragma unroll
    for (int u = 0; u < 4; ++u)
#pragma unroll
        for (int v = 0; v < 4; ++v) acc[u][v] = 0.0;

    for (int k0 = 0; k0 < 128; k0 += 64) {
        __syncthreads();
        for (int e = threadIdx.x; e < 64 * 64; e += 256) {
            int r = e >> 6, c = e & 63;
            As[r][c] = A[(size_t)(m0 + r) * 128 + k0 + c];
            int j = j0 + r;
            double wv;
            if (mode == 0) wv = (j < 128) ? (double)W[j * 256 + k0 + c] : (double)W[(j - 128) * 256 + 128 + k0 + c];
            else           wv = (double)W[j * 128 + k0 + c];
            Ws[r][c] = wv;
        }
        __syncthreads();
        for (int c = 0; c < 64; c += 2) {
            double a0[4], a1[4], w0[4], w1[4];
#pragma unroll
            for (int u = 0; u < 4; ++u) { a0[u] = As[ri + 16 * u][c]; a1[u] = As[ri + 16 * u][c + 1]; }
#pragma unroll
            for (int v = 0; v < 4; ++v) { w0[v] = Ws[ci + 16 * v][c]; w1[v] = Ws[ci + 16 * v][c + 1]; }
#pragma unroll
            for (int u = 0; u < 4; ++u)
#pragma unroll
                for (int v = 0; v < 4; ++v)
                    acc[u][v] = fma(a1[u], w1[v], fma(a0[u], w0[v], acc[u][v]));
        }
    }
#pragma unroll
    for (int u = 0; u < 4; ++u) {
        int row = m0 + ri + 16 * u;
#pragma unroll
        for (int v = 0; v < 4; ++v) {
            int jl = ci + 16 * v;
            double val = acc[u][v];
            if (mode == 0) {
                out[(size_t)row * 256 + j0 + jl] = val;
            } else {
                int jg = j0 + jl;
                double z = (val + (double)bias[jg]) * (double)gamma[jg] + (double)beta[jg];
                if (mode == 1) {
                    out[(size_t)row * 128 + jg] = gelu64(z);
                } else {
                    out[(size_t)row * 128 + jg] = z;
                    out32[(size_t)row * 128 + jg] = (float)z;
                }
            }
        }
    }
}

// ---------------- combine64 (in-place residual): xt += max_k gelu((G1+b-G2_i+G2_j)*gamma+beta)
__global__ __launch_bounds__(256) void combine64_kernel(
    double* __restrict__ xt, const double* __restrict__ G,
    const int* __restrict__ idx, const float* __restrict__ bias,
    const float* __restrict__ gamma, const float* __restrict__ beta)
{
    const int row = blockIdx.x * 2 + (threadIdx.x >> 7);
    const int o = threadIdx.x & 127;
    const int b = row >> 11;
    const double* Gb = G + (size_t)(b * 2048) * 256;
    const int* id9 = idx + (size_t)row * 9;
    double g1  = G[(size_t)row * 256 + o];
    double g2i = G[(size_t)row * 256 + 128 + o];
    double base = g1 + (double)bias[o] - g2i;
    double gm = (double)gamma[o], bt = (double)beta[o];
    double mx = -1.0e300;
#pragma unroll
    for (int k = 0; k < 9; ++k) {
        int j = id9[k];
        double h = base + Gb[(size_t)j * 256 + 128 + o];
        double z = h * gm + bt;
        mx = fmax(mx, gelu64(z));
    }
    xt[(size_t)row * 128 + o] += mx;
}

// ---------------- f32 GEMM (block-2 value path). modes as gemm64
__global__ __launch_bounds__(256) void gemm128_kernel(
    const float* __restrict__ A, const float* __restrict__ W,
    const float* __restrict__ bias, const float* __restrict__ gamma,
    const float* __restrict__ beta, float* __restrict__ out, int mode)
{
    __shared__ float Al[128][132];
    __shared__ float Wl[128][132];
    const int m0 = blockIdx.x * 128;
    const int j0 = blockIdx.y * 128;
    for (int e = threadIdx.x; e < 128 * 32; e += 256) {
        int r = e >> 5, q = e & 31;
        *(float4*)&Al[r][q * 4] = *(const float4*)(A + (size_t)(m0 + r) * 128 + q * 4);
    }
    for (int e = threadIdx.x; e < 128 * 32; e += 256) {
        int jj = e >> 5, q = e & 31;
        int c = q * 4;
        const float* src;
        if (mode == 0) {
            int j = j0 + jj;
            src = (j < 128) ? (W + j * 256 + c) : (W + (j - 128) * 256 + 128 + c);
        } else {
            src = W + jj * 128 + c;
        }
        *(float4*)&Wl[jj][c] = *(const float4*)src;
    }
    __syncthreads();
    const int ri = threadIdx.x >> 4, ci = threadIdx.x & 15;
    float acc[8][8];
#pragma unroll
    for (int u = 0; u < 8; ++u)
#pragma unroll
        for (int v = 0; v < 8; ++v) acc[u][v] = 0.0f;
    for (int c = 0; c < 128; c += 4) {
        float4 a4[8];
#pragma unroll
        for (int u = 0; u < 8; ++u) a4[u] = *(const float4*)&Al[ri + 16 * u][c];
#pragma unroll
        for (int v = 0; v < 8; ++v) {
            float4 w4 = *(const float4*)&Wl[ci + 16 * v][c];
#pragma unroll
            for (int u = 0; u < 8; ++u) {
                acc[u][v] = fmaf(a4[u].x, w4.x, fmaf(a4[u].y, w4.y,
                            fmaf(a4[u].z, w4.z, fmaf(a4[u].w, w4.w, acc[u][v]))));
            }
        }
    }
#pragma unroll
    for (int u = 0; u < 8; ++u) {
        int row = m0 + ri + 16 * u;
#pragma unroll
        for (int v = 0; v < 8; ++v) {
            int j = ci + 16 * v;
            float val = acc[u][v];
            if (mode == 0) {
                out[(size_t)row * 256 + j0 + j] = val;
            } else if (mode == 1) {
                float z = (val + bias[j]) * gamma[j] + beta[j];
                out[(size_t)row * 128 + j] = gelu_exact(z);
            } else {
                float z = (val + bias[j]) * gamma[j] + beta[j];
                out[(size_t)row * 128 + j] = z;
            }
        }
    }
}

// ---------------- combine f32 (block 2; in-place safe: reads only own row of xt)
__global__ __launch_bounds__(256) void combine_kernel(
    const float* __restrict__ xt, const float* __restrict__ G,
    const int* __restrict__ idx, const float* __restrict__ bias,
    const float* __restrict__ gamma, const float* __restrict__ beta,
    float* __restrict__ xt2)
{
    const int row = blockIdx.x * 2 + (threadIdx.x >> 7);
    const int o = threadIdx.x & 127;
    const int b = row >> 11;
    const float* Gb = G + (size_t)(b * 2048) * 256;
    const int* id9 = idx + (size_t)row * 9;
    float g1  = G[(size_t)row * 256 + o];
    float g2i = G[(size_t)row * 256 + 128 + o];
    float base = g1 + bias[o] - g2i;
    float gm = gamma[o], bt = beta[o];
    float mx = -3.4e38f;
#pragma unroll
    for (int k = 0; k < 9; ++k) {
        int j = id9[k];
        float h = base + Gb[(size_t)j * 256 + 128 + o];
        float z = h * gm + bt;
        mx = fmaxf(mx, gelu_exact(z));
    }
    xt2[(size_t)row * 128 + o] = xt[(size_t)row * 128 + o] + mx;
}

extern "C" void kernel_launch(void* const* d_in, const int* in_sizes, int n_in,
                              void* d_out, int out_size, void* d_ws, size_t ws_size,
                              hipStream_t stream)
{
    const float* ts       = (const float*)d_in[0];
    const float* conv1_w  = (const float*)d_in[1];
    const float* conv1_b  = (const float*)d_in[2];
    const float* conv2_w  = (const float*)d_in[3];
    const float* conv2_b  = (const float*)d_in[4];
    const float* gconv_w  = (const float*)d_in[5];
    const float* gconv_b  = (const float*)d_in[6];
    const float* gconv_g  = (const float*)d_in[7];
    const float* gconv_be = (const float*)d_in[8];
    const float* ffn1_w   = (const float*)d_in[9];
    const float* ffn1_b   = (const float*)d_in[10];
    const float* ffn1_g   = (const float*)d_in[11];
    const float* ffn1_be  = (const float*)d_in[12];
    const float* ffn2_w   = (const float*)d_in[13];
    const float* ffn2_b   = (const float*)d_in[14];
    const float* ffn2_g   = (const float*)d_in[15];
    const float* ffn2_be  = (const float*)d_in[16];
    (void)in_sizes; (void)n_in; (void)out_size; (void)ws_size;

    // ---- workspace layout (byte offsets), lifetime-overlaid; peak ~101.8 MB ----
    char* base = (char*)d_ws;
    double*         XT64   = (double*)(base + 0);            // 33.55 MB
    double*         H1_64  = (double*)(base + 33554432);     // 16.78 MB (conv phase only)
    unsigned short* XH     = (unsigned short*)(base + 33554432); // 8.39 MB (norm -> knn)
    unsigned short* XM     = (unsigned short*)(base + 41943040); // 8.39 MB (norm -> knn)
    int*            CAND   = (int*)   (base + 50331648);     // 2.10 MB  (knn -> rescore)
    double*         XN64_1 = (double*)(base + 52428800);     // 33.55 MB (blk1 norm -> rescore; dies before G64)
    double*         SQ64_1 = (double*)(base + 85983232);     // 0.26 MB
    double*         G64    = (double*)(base + 33554432);     // 67.11 MB (gemm0 -> combine, blk1)
    double*         H64    = (double*)(base + 33554432);     // 33.55 MB (ffn1 -> ffn2, blk1)
    float*          XT32P  = (float*) (base + 67108864);     // 16.78 MB (blk1 ffn2 -> blk2 value path)
    int*            IDX    = (int*)   (base + 100663296);    // 1.18 MB  (rescore -> combine)
    float*          G32    = (float*) (base + 33554432);     // 33.55 MB (blk2)
    float*          H32    = (float*) (base + 33554432);     // 16.78 MB (blk2 ffn)
    double*         XN64_2 = XT64;                           // blk2: in-place over XT64 (dead after blk2 norm)
    double*         SQ64_2 = SQ64_1;

    float* fout = (float*)d_out;

    conv1_kernel64<<<dim3(64, 16), 256, 0, stream>>>(ts, conv1_w, conv1_b, H1_64);
    conv2_kernel64<<<dim3(64, 16), 256, 0, stream>>>(H1_64, conv2_w, conv2_b, XT64);

    // ---------- block 1 (f64 value path; indices exact) ----------
    norm_planes_kernel<<<8192, 256, 0, stream>>>(XT64, XH, XM, XN64_1, SQ64_1);
    knn_mfma4_kernel<<<256, 512, 0, stream>>>(XH, XM, CAND);
    rescore2_kernel<<<8192, 256, 0, stream>>>(XN64_1, SQ64_1, CAND, IDX);
    gemm64_kernel<<<dim3(512, 4), 256, 0, stream>>>(
        XT64, gconv_w, nullptr, nullptr, nullptr, G64, nullptr, 0);
    combine64_kernel<<<16384, 256, 0, stream>>>(
        XT64, G64, IDX, gconv_b, gconv_g, gconv_be);
    gemm64_kernel<<<dim3(512, 2), 256, 0, stream>>>(
        XT64, ffn1_w, ffn1_b, ffn1_g, ffn1_be, H64, nullptr, 1);
    gemm64_kernel<<<dim3(512, 2), 256, 0, stream>>>(
        H64, ffn2_w, ffn2_b, ffn2_g, ffn2_be, XT64, XT32P, 2);

    // ---------- block 2 (indices exact via f64; value path f32) ----------
    norm_planes_kernel<<<8192, 256, 0, stream>>>(XT64, XH, XM, XN64_2, SQ64_2);
    knn_mfma4_kernel<<<256, 512, 0, stream>>>(XH, XM, CAND);
    rescore2_kernel<<<8192, 256, 0, stream>>>(XN64_2, SQ64_2, CAND, IDX);
    gemm128_kernel<<<dim3(256, 2), 256, 0, stream>>>(
        XT32P, gconv_w + 32768, nullptr, nullptr, nullptr, G32, 0);
    combine_kernel<<<16384, 256, 0, stream>>>(
        XT32P, G32, IDX, gconv_b + 128, gconv_g + 128, gconv_be + 128, XT32P);
    gemm128_kernel<<<dim3(256, 1), 256, 0, stream>>>(
        XT32P, ffn1_w + 16384, ffn1_b + 128, ffn1_g + 128, ffn1_be + 128, H32, 1);
    gemm128_kernel<<<dim3(256, 1), 256, 0, stream>>>(
        H32, ffn2_w + 16384, ffn2_b + 128, ffn2_g + 128, ffn2_be + 128, fout, 2);
}